// Round 1
// baseline (306.051 us; speedup 1.0000x reference)
//
#include <hip/hip_runtime.h>

#define B_   8
#define N_   8192
#define S_   2048
#define D1_  128
#define D2_  256
#define C1_  384
#define O_   256
#define BN_  (B_*N_)   // 65536

typedef __bf16 bf16;
typedef __bf16 bf16x8_t __attribute__((ext_vector_type(8)));
typedef float  f32x4_t  __attribute__((ext_vector_type(4)));

// ---------------- workspace layout ----------------
// idx planes: 3 * 65536 * 4B = 786432
// w   planes: 3 * 65536 * 4B = 786432
// x panels  : B*48*N*8 bf16  = 50331648
// z panels  : B*32*N*8 bf16  = 33554432
// ss1/ss2   : 512 floats each
static const size_t OFF_IDX = 0;
static const size_t OFF_W   = 786432;
static const size_t OFF_XP  = 1572864;
static const size_t OFF_Z   = 51904512;
static const size_t OFF_SS1 = 85458944;
static const size_t OFF_SS2 = 85460992;

// ---------------- kernel 1: points1 -> x panels 0..15 (bf16, [B][48][N][8]) ----------------
__global__ __launch_bounds__(256) void k_conv_p1(const float* __restrict__ p1, bf16* __restrict__ xp) {
  const int g  = blockIdx.x * 256 + threadIdx.x;   // B*16*2048 = 262144 threads
  const int n4 = g & 2047;
  const int c8 = (g >> 11) & 15;
  const int b  = g >> 15;
  const int n  = n4 * 4;
  const float* src = p1 + ((size_t)b * D1_ + c8 * 8) * N_ + n;
  bf16x8_t o0, o1, o2, o3;
  #pragma unroll
  for (int j = 0; j < 8; ++j) {
    float4 v = *(const float4*)(src + (size_t)j * N_);
    o0[j] = (bf16)v.x; o1[j] = (bf16)v.y; o2[j] = (bf16)v.z; o3[j] = (bf16)v.w;
  }
  bf16* dst = xp + (((size_t)b * 48 + c8) * N_ + n) * 8;
  *(bf16x8_t*)(dst)      = o0;
  *(bf16x8_t*)(dst + 8)  = o1;
  *(bf16x8_t*)(dst + 16) = o2;
  *(bf16x8_t*)(dst + 24) = o3;
}

// ---------------- kernel 2: 3-NN search ----------------
__device__ __forceinline__ void ins3(float d, int i,
                                     float& d0, float& d1, float& d2,
                                     int& i0, int& i1, int& i2) {
  const bool c2 = d < d2, c1 = d < d1, c0 = d < d0;
  const float nd2 = c1 ? d1 : (c2 ? d : d2); const int ni2 = c1 ? i1 : (c2 ? i : i2);
  const float nd1 = c0 ? d0 : (c1 ? d : d1); const int ni1 = c0 ? i0 : (c1 ? i : i1);
  d0 = c0 ? d : d0; i0 = c0 ? i : i0;
  d1 = nd1; i1 = ni1; d2 = nd2; i2 = ni2;
}

__global__ __launch_bounds__(256) void k_nn3(const float* __restrict__ xyz1, const float* __restrict__ xyz2,
                                             int* __restrict__ idxw, float* __restrict__ www) {
  __shared__ float sx[S_], sy[S_], sz[S_];
  const int b = blockIdx.y;
  const float* x2 = xyz2 + (size_t)b * 3 * S_;
  for (int i = threadIdx.x; i < S_; i += 256) {
    sx[i] = x2[i]; sy[i] = x2[S_ + i]; sz[i] = x2[2 * S_ + i];
  }
  __syncthreads();
  const int n = blockIdx.x * 256 + threadIdx.x;
  const float* x1 = xyz1 + (size_t)b * 3 * N_;
  const float px = x1[n], py = x1[N_ + n], pz = x1[2 * N_ + n];
  float d0 = 3.4e38f, d1 = 3.4e38f, d2 = 3.4e38f;
  int   i0 = 0, i1 = 0, i2 = 0;
  for (int s = 0; s < S_; s += 4) {
    const float4 qx = *(const float4*)&sx[s];
    const float4 qy = *(const float4*)&sy[s];
    const float4 qz = *(const float4*)&sz[s];
    float ax, ay, az;
    ax = px - qx.x; ay = py - qy.x; az = pz - qz.x; const float da = fmaf(ax, ax, fmaf(ay, ay, az * az));
    ax = px - qx.y; ay = py - qy.y; az = pz - qz.y; const float db = fmaf(ax, ax, fmaf(ay, ay, az * az));
    ax = px - qx.z; ay = py - qy.z; az = pz - qz.z; const float dc = fmaf(ax, ax, fmaf(ay, ay, az * az));
    ax = px - qx.w; ay = py - qy.w; az = pz - qz.w; const float dd = fmaf(ax, ax, fmaf(ay, ay, az * az));
    const float dmin = fminf(fminf(da, db), fminf(dc, dd));
    if (__any(dmin < d2)) {
      ins3(da, s,     d0, d1, d2, i0, i1, i2);
      ins3(db, s + 1, d0, d1, d2, i0, i1, i2);
      ins3(dc, s + 2, d0, d1, d2, i0, i1, i2);
      ins3(dd, s + 3, d0, d1, d2, i0, i1, i2);
    }
  }
  const float r0 = 1.f / (d0 + 1e-8f), r1 = 1.f / (d1 + 1e-8f), r2 = 1.f / (d2 + 1e-8f);
  const float inv = 1.f / (r0 + r1 + r2);
  const int bn = b * N_ + n;
  idxw[bn] = i0; idxw[BN_ + bn] = i1; idxw[2 * BN_ + bn] = i2;
  www[bn] = r0 * inv; www[BN_ + bn] = r1 * inv; www[2 * BN_ + bn] = r2 * inv;
}

// ---------------- kernel 3: interpolation -> x panels 16..47 ----------------
__global__ __launch_bounds__(256) void k_interp(const float* __restrict__ p2, const int* __restrict__ idxw,
                                                const float* __restrict__ www, bf16* __restrict__ xp) {
  __shared__ float rows[4][S_];   // 32 KB
  const int b = blockIdx.y;
  const int n = blockIdx.x * 256 + threadIdx.x;
  const int bn = b * N_ + n;
  const int j0 = idxw[bn], j1 = idxw[BN_ + bn], j2 = idxw[2 * BN_ + bn];
  const float w0 = www[bn], w1 = www[BN_ + bn], w2 = www[2 * BN_ + bn];
  const float* src = p2 + (size_t)b * D2_ * S_;
  #pragma unroll 1
  for (int c8 = 0; c8 < 32; ++c8) {
    bf16x8_t out;
    #pragma unroll
    for (int h = 0; h < 2; ++h) {
      __syncthreads();
      const float4* s4 = (const float4*)(src + (size_t)(c8 * 8 + h * 4) * S_);
      float4* r4 = (float4*)rows;
      #pragma unroll
      for (int i = 0; i < 8; ++i) r4[threadIdx.x + i * 256] = s4[threadIdx.x + i * 256];
      __syncthreads();
      #pragma unroll
      for (int j = 0; j < 4; ++j)
        out[h * 4 + j] = (bf16)(w0 * rows[j][j0] + w1 * rows[j][j1] + w2 * rows[j][j2]);
    }
    *(bf16x8_t*)(xp + (((size_t)b * 48 + 16 + c8) * N_ + (size_t)n) * 8) = out;
  }
}

// ---------------- kernel 4: GEMM  Y[b][o][n] = sum_k W[o][k] * X[b][k][n] + bias[o] ----------------
// X in panel layout [B][K/8][N][8] bf16; W fp32 row-major [256][K]; Y fp32 [B][256][N]
template<int K>
__global__ __launch_bounds__(256) void k_gemm(const float* __restrict__ W, const float* __restrict__ bias,
                                              const bf16* __restrict__ X, float* __restrict__ Y) {
  __shared__ bf16 As[128][40];   // pad to 40 elems (80B): 16B-aligned b128, <=2-way conflicts
  __shared__ bf16 Bt[128][40];
  const int tid = threadIdx.x;
  const int lane = tid & 63, wid = tid >> 6;
  const int wr = wid >> 1, wc = wid & 1;
  const int n0 = blockIdx.x * 128;
  const int m0 = blockIdx.y * 128;
  const int b  = blockIdx.z;
  const int l15 = lane & 15, l4 = lane >> 4;

  f32x4_t acc[4][4];
  #pragma unroll
  for (int i = 0; i < 4; ++i)
    #pragma unroll
    for (int j = 0; j < 4; ++j) { f32x4_t z = {0.f, 0.f, 0.f, 0.f}; acc[i][j] = z; }

  const int arow = tid >> 1, ac0 = (tid & 1) * 16;
  const bf16* Xb = X + (size_t)b * (K / 8) * ((size_t)N_ * 8);

  for (int kt = 0; kt < K; kt += 32) {
    { // A stage (fp32 -> bf16)
      const float* s = W + (size_t)(m0 + arow) * K + kt + ac0;
      const float4 f0 = *(const float4*)(s);
      const float4 f1 = *(const float4*)(s + 4);
      const float4 f2 = *(const float4*)(s + 8);
      const float4 f3 = *(const float4*)(s + 12);
      bf16x8_t h0, h1;
      h0[0] = (bf16)f0.x; h0[1] = (bf16)f0.y; h0[2] = (bf16)f0.z; h0[3] = (bf16)f0.w;
      h0[4] = (bf16)f1.x; h0[5] = (bf16)f1.y; h0[6] = (bf16)f1.z; h0[7] = (bf16)f1.w;
      h1[0] = (bf16)f2.x; h1[1] = (bf16)f2.y; h1[2] = (bf16)f2.z; h1[3] = (bf16)f2.w;
      h1[4] = (bf16)f3.x; h1[5] = (bf16)f3.y; h1[6] = (bf16)f3.z; h1[7] = (bf16)f3.w;
      *(bf16x8_t*)&As[arow][ac0]     = h0;
      *(bf16x8_t*)&As[arow][ac0 + 8] = h1;
    }
    { // B stage from panel layout: wave wid loads k-chunk (kt/8 + wid), 128 n
      const bf16* s = Xb + ((size_t)(kt / 8 + wid)) * ((size_t)N_ * 8) + (size_t)n0 * 8;
      const bf16x8_t q0 = *(const bf16x8_t*)(s + (size_t)lane * 8);
      const bf16x8_t q1 = *(const bf16x8_t*)(s + (size_t)(lane + 64) * 8);
      *(bf16x8_t*)&Bt[lane][wid * 8]      = q0;
      *(bf16x8_t*)&Bt[lane + 64][wid * 8] = q1;
    }
    __syncthreads();
    bf16x8_t af[4], bfr[4];
    #pragma unroll
    for (int mi = 0; mi < 4; ++mi) af[mi]  = *(const bf16x8_t*)&As[wr * 64 + mi * 16 + l15][l4 * 8];
    #pragma unroll
    for (int ni = 0; ni < 4; ++ni) bfr[ni] = *(const bf16x8_t*)&Bt[wc * 64 + ni * 16 + l15][l4 * 8];
    #pragma unroll
    for (int mi = 0; mi < 4; ++mi)
      #pragma unroll
      for (int ni = 0; ni < 4; ++ni)
        acc[mi][ni] = __builtin_amdgcn_mfma_f32_16x16x32_bf16(af[mi], bfr[ni], acc[mi][ni], 0, 0, 0);
    __syncthreads();
  }
  float* Yb = Y + (size_t)b * O_ * N_;
  #pragma unroll
  for (int mi = 0; mi < 4; ++mi)
    #pragma unroll
    for (int j = 0; j < 4; ++j) {
      const int o = m0 + wr * 64 + mi * 16 + l4 * 4 + j;
      const float bv = bias[o];
      #pragma unroll
      for (int ni = 0; ni < 4; ++ni) {
        const int nn = n0 + wc * 64 + ni * 16 + l15;
        Yb[(size_t)o * N_ + nn] = acc[mi][ni][j] + bv;
      }
    }
}

// ---------------- kernel 5: per-channel BN stats -> scale/shift ----------------
__global__ __launch_bounds__(256) void k_stats(const float* __restrict__ Y, const float* __restrict__ g,
                                               const float* __restrict__ be, float* __restrict__ ss) {
  const int c = blockIdx.x;
  float sum = 0.f, sq = 0.f;
  for (int b = 0; b < B_; ++b) {
    const float4* p = (const float4*)(Y + ((size_t)b * O_ + c) * N_);
    for (int i = threadIdx.x; i < N_ / 4; i += 256) {
      const float4 v = p[i];
      sum += v.x + v.y + v.z + v.w;
      sq = fmaf(v.x, v.x, sq); sq = fmaf(v.y, v.y, sq);
      sq = fmaf(v.z, v.z, sq); sq = fmaf(v.w, v.w, sq);
    }
  }
  #pragma unroll
  for (int off = 32; off; off >>= 1) { sum += __shfl_down(sum, off); sq += __shfl_down(sq, off); }
  __shared__ float w1s[4], w2s[4];
  const int wid = threadIdx.x >> 6;
  if ((threadIdx.x & 63) == 0) { w1s[wid] = sum; w2s[wid] = sq; }
  __syncthreads();
  if (threadIdx.x == 0) {
    const float s = w1s[0] + w1s[1] + w1s[2] + w1s[3];
    const float q = w2s[0] + w2s[1] + w2s[2] + w2s[3];
    const float mean = s * (1.f / 65536.f);
    const float var  = q * (1.f / 65536.f) - mean * mean;
    const float rstd = rsqrtf(var + 1e-5f);
    const float sc = g[c] * rstd;
    ss[c] = sc; ss[O_ + c] = be[c] - mean * sc;
  }
}

// ---------------- kernel 6: z = bf16(relu(y*s+sh)) into panel layout [B][32][N][8] ----------------
__global__ __launch_bounds__(256) void k_apply(const float* __restrict__ Y, const float* __restrict__ ss,
                                               bf16* __restrict__ Z) {
  const int n  = blockIdx.x * 256 + threadIdx.x;
  const int c8 = blockIdx.y;
  const int b  = blockIdx.z;
  bf16x8_t out;
  #pragma unroll
  for (int j = 0; j < 8; ++j) {
    const int c = c8 * 8 + j;
    float v = Y[((size_t)b * O_ + c) * N_ + n];
    v = fmaxf(fmaf(v, ss[c], ss[O_ + c]), 0.f);
    out[j] = (bf16)v;
  }
  *(bf16x8_t*)(Z + (((size_t)b * 32 + c8) * N_ + (size_t)n) * 8) = out;
}

// ---------------- kernel 7: final BN+ReLU in place (fp32) ----------------
__global__ __launch_bounds__(256) void k_final(float* __restrict__ Y, const float* __restrict__ ss) {
  const size_t g = ((size_t)blockIdx.x * 256 + threadIdx.x) * 8;
  const int c = (int)((g >> 13) & 255);
  const float sc = ss[c], sh = ss[O_ + c];
  float4 v0 = *(float4*)(Y + g), v1 = *(float4*)(Y + g + 4);
  v0.x = fmaxf(fmaf(v0.x, sc, sh), 0.f); v0.y = fmaxf(fmaf(v0.y, sc, sh), 0.f);
  v0.z = fmaxf(fmaf(v0.z, sc, sh), 0.f); v0.w = fmaxf(fmaf(v0.w, sc, sh), 0.f);
  v1.x = fmaxf(fmaf(v1.x, sc, sh), 0.f); v1.y = fmaxf(fmaf(v1.y, sc, sh), 0.f);
  v1.z = fmaxf(fmaf(v1.z, sc, sh), 0.f); v1.w = fmaxf(fmaf(v1.w, sc, sh), 0.f);
  *(float4*)(Y + g) = v0; *(float4*)(Y + g + 4) = v1;
}

extern "C" void kernel_launch(void* const* d_in, const int* in_sizes, int n_in,
                              void* d_out, int out_size, void* d_ws, size_t ws_size,
                              hipStream_t stream) {
  const float* xyz1    = (const float*)d_in[0];
  const float* xyz2    = (const float*)d_in[1];
  const float* points1 = (const float*)d_in[2];
  const float* points2 = (const float*)d_in[3];
  const float* W1  = (const float*)d_in[4];
  const float* b1  = (const float*)d_in[5];
  const float* g1  = (const float*)d_in[6];
  const float* be1 = (const float*)d_in[7];
  const float* W2  = (const float*)d_in[8];
  const float* b2  = (const float*)d_in[9];
  const float* g2  = (const float*)d_in[10];
  const float* be2 = (const float*)d_in[11];
  float* Y = (float*)d_out;
  char*  ws = (char*)d_ws;
  int*   idxw = (int*)(ws + OFF_IDX);
  float* www  = (float*)(ws + OFF_W);
  bf16*  xp   = (bf16*)(ws + OFF_XP);
  bf16*  Z    = (bf16*)(ws + OFF_Z);
  float* ss1  = (float*)(ws + OFF_SS1);
  float* ss2  = (float*)(ws + OFF_SS2);

  hipLaunchKernelGGL(k_conv_p1, dim3(1024), dim3(256), 0, stream, points1, xp);
  hipLaunchKernelGGL(k_nn3, dim3(32, 8), dim3(256), 0, stream, xyz1, xyz2, idxw, www);
  hipLaunchKernelGGL(k_interp, dim3(32, 8), dim3(256), 0, stream, points2, idxw, www, xp);
  hipLaunchKernelGGL((k_gemm<384>), dim3(64, 2, 8), dim3(256), 0, stream, W1, b1, xp, Y);
  hipLaunchKernelGGL(k_stats, dim3(256), dim3(256), 0, stream, Y, g1, be1, ss1);
  hipLaunchKernelGGL(k_apply, dim3(32, 32, 8), dim3(256), 0, stream, Y, ss1, Z);
  hipLaunchKernelGGL((k_gemm<256>), dim3(64, 2, 8), dim3(256), 0, stream, W2, b2, Z, Y);
  hipLaunchKernelGGL(k_stats, dim3(256), dim3(256), 0, stream, Y, g2, be2, ss2);
  hipLaunchKernelGGL(k_final, dim3(8192), dim3(256), 0, stream, Y, ss2);
}

// Round 2
// 276.798 us; speedup vs baseline: 1.1057x; 1.1057x over previous
//
#include <hip/hip_runtime.h>

#define B_   8
#define N_   8192
#define S_   2048
#define D1_  128
#define D2_  256
#define C1_  384
#define O_   256
#define BN_  (B_*N_)   // 65536

typedef __bf16 bf16;
typedef __bf16 bf16x8_t __attribute__((ext_vector_type(8)));
typedef float  f32x4_t  __attribute__((ext_vector_type(4)));

// ---------------- workspace layout ----------------
static const size_t OFF_IDX = 0;
static const size_t OFF_W   = 786432;
static const size_t OFF_XP  = 1572864;
static const size_t OFF_Z   = 51904512;
static const size_t OFF_SS1 = 85458944;
static const size_t OFF_SS2 = 85460992;

// ---------------- kernel 1: points1 -> x panels 0..15 (bf16, [B][48][N][8]) ----------------
__global__ __launch_bounds__(256) void k_conv_p1(const float* __restrict__ p1, bf16* __restrict__ xp) {
  const int g  = blockIdx.x * 256 + threadIdx.x;
  const int n4 = g & 2047;
  const int c8 = (g >> 11) & 15;
  const int b  = g >> 15;
  const int n  = n4 * 4;
  const float* src = p1 + ((size_t)b * D1_ + c8 * 8) * N_ + n;
  bf16x8_t o0, o1, o2, o3;
  #pragma unroll
  for (int j = 0; j < 8; ++j) {
    float4 v = *(const float4*)(src + (size_t)j * N_);
    o0[j] = (bf16)v.x; o1[j] = (bf16)v.y; o2[j] = (bf16)v.z; o3[j] = (bf16)v.w;
  }
  bf16* dst = xp + (((size_t)b * 48 + c8) * N_ + n) * 8;
  *(bf16x8_t*)(dst)      = o0;
  *(bf16x8_t*)(dst + 8)  = o1;
  *(bf16x8_t*)(dst + 16) = o2;
  *(bf16x8_t*)(dst + 24) = o3;
}

// ---------------- kernel 2: 3-NN search (branchless, 2 pts/thread, 4 S-chunks/block) ----------
__device__ __forceinline__ void ins3(float d, int i,
                                     float& d0, float& d1, float& d2,
                                     int& i0, int& i1, int& i2) {
  const bool c2 = d < d2, c1 = d < d1, c0 = d < d0;
  const float nd2 = c1 ? d1 : (c2 ? d : d2); const int ni2 = c1 ? i1 : (c2 ? i : i2);
  const float nd1 = c0 ? d0 : (c1 ? d : d1); const int ni1 = c0 ? i0 : (c1 ? i : i1);
  d0 = c0 ? d : d0; i0 = c0 ? i : i0;
  d1 = nd1; i1 = ni1; d2 = nd2; i2 = ni2;
}

// branchless sorted top-3 insert: e0<=e1<=e2 invariant
#define INS_BL(E, SI, e0, e1, e2, i0, i1, i2)            \
  {                                                      \
    const bool l0 = (E) < e0, l1 = (E) < e1, l2 = (E) < e2; \
    const int  t1 = l0 ? i0 : (l1 ? (SI) : i1);          \
    const int  t2 = l1 ? i1 : (l2 ? (SI) : i2);          \
    i0 = l0 ? (SI) : i0; i1 = t1; i2 = t2;               \
    const float m1 = fminf(fmaxf((E), e0), e1);          \
    const float m2 = fminf(fmaxf((E), e1), e2);          \
    e0 = fminf((E), e0); e1 = m1; e2 = m2;               \
  }

__global__ __launch_bounds__(256) void k_nn3(const float* __restrict__ xyz1, const float* __restrict__ xyz2,
                                             int* __restrict__ idxw, float* __restrict__ www) {
  __shared__ float4 sq[4][S_ / 4];   // planes: x, y, z, |q|^2  (32 KB)
  __shared__ float  pd[4][128][3];   // per-chunk partial top-3 dists (6 KB)
  __shared__ int    pi[4][128][3];   // per-chunk partial top-3 idx   (6 KB)
  const int tid  = threadIdx.x;
  const int lane = tid & 63, w = tid >> 6;     // w = S-chunk 0..3
  const int b     = blockIdx.y;
  const int nbase = blockIdx.x * 128;

  // stage xyz2 + |q|^2
  const float* x2 = xyz2 + (size_t)b * 3 * S_;
  for (int j = tid; j < S_ / 4; j += 256) {
    const float4 x = *(const float4*)(x2 + 4 * j);
    const float4 y = *(const float4*)(x2 + S_ + 4 * j);
    const float4 z = *(const float4*)(x2 + 2 * S_ + 4 * j);
    float4 qq;
    qq.x = fmaf(x.x, x.x, fmaf(y.x, y.x, z.x * z.x));
    qq.y = fmaf(x.y, x.y, fmaf(y.y, y.y, z.y * z.y));
    qq.z = fmaf(x.z, x.z, fmaf(y.z, y.z, z.z * z.z));
    qq.w = fmaf(x.w, x.w, fmaf(y.w, y.w, z.w * z.w));
    sq[0][j] = x; sq[1][j] = y; sq[2][j] = z; sq[3][j] = qq;
  }

  // two query points per thread
  const int n_a = nbase + lane, n_b = n_a + 64;
  const float* x1 = xyz1 + (size_t)b * 3 * N_;
  const float pax = x1[n_a], pay = x1[N_ + n_a], paz = x1[2 * N_ + n_a];
  const float pbx = x1[n_b], pby = x1[N_ + n_b], pbz = x1[2 * N_ + n_b];
  const float ax = -2.f * pax, ay = -2.f * pay, az = -2.f * paz;
  const float bx = -2.f * pbx, by = -2.f * pby, bz = -2.f * pbz;
  __syncthreads();

  float ea0 = 3.4e38f, ea1 = 3.4e38f, ea2 = 3.4e38f;
  float eb0 = 3.4e38f, eb1 = 3.4e38f, eb2 = 3.4e38f;
  int ia0 = 0, ia1 = 0, ia2 = 0, ib0 = 0, ib1 = 0, ib2 = 0;

  const int jb = w * (S_ / 16);    // 128 float4 groups per chunk
  #pragma unroll 2
  for (int j = jb; j < jb + S_ / 16; ++j) {
    const float4 qx = sq[0][j], qy = sq[1][j], qz = sq[2][j], qq = sq[3][j];
    #define CAND(C, SI)                                                    \
      {                                                                    \
        const float Ea = fmaf(ax, qx.C, fmaf(ay, qy.C, fmaf(az, qz.C, qq.C))); \
        const float Eb = fmaf(bx, qx.C, fmaf(by, qy.C, fmaf(bz, qz.C, qq.C))); \
        INS_BL(Ea, SI, ea0, ea1, ea2, ia0, ia1, ia2);                      \
        INS_BL(Eb, SI, eb0, eb1, eb2, ib0, ib1, ib2);                      \
      }
    CAND(x, 4 * j + 0)
    CAND(y, 4 * j + 1)
    CAND(z, 4 * j + 2)
    CAND(w, 4 * j + 3)
    #undef CAND
  }

  // add |p|^2 back (monotone shift) and store partials
  const float ppa = fmaf(pax, pax, fmaf(pay, pay, paz * paz));
  const float ppb = fmaf(pbx, pbx, fmaf(pby, pby, pbz * pbz));
  pd[w][lane][0] = ea0 + ppa; pd[w][lane][1] = ea1 + ppa; pd[w][lane][2] = ea2 + ppa;
  pi[w][lane][0] = ia0; pi[w][lane][1] = ia1; pi[w][lane][2] = ia2;
  pd[w][lane + 64][0] = eb0 + ppb; pd[w][lane + 64][1] = eb1 + ppb; pd[w][lane + 64][2] = eb2 + ppb;
  pi[w][lane + 64][0] = ib0; pi[w][lane + 64][1] = ib1; pi[w][lane + 64][2] = ib2;
  __syncthreads();

  // merge 4 chunks (threads 0..127, one n each)
  if (tid < 128) {
    float d0 = pd[0][tid][0], d1 = pd[0][tid][1], d2 = pd[0][tid][2];
    int   i0 = pi[0][tid][0], i1 = pi[0][tid][1], i2 = pi[0][tid][2];
    #pragma unroll
    for (int ck = 1; ck < 4; ++ck)
      #pragma unroll
      for (int k = 0; k < 3; ++k)
        ins3(pd[ck][tid][k], pi[ck][tid][k], d0, d1, d2, i0, i1, i2);
    const float r0 = 1.f / (d0 + 1e-8f), r1 = 1.f / (d1 + 1e-8f), r2 = 1.f / (d2 + 1e-8f);
    const float inv = 1.f / (r0 + r1 + r2);
    const int bn = b * N_ + nbase + tid;
    idxw[bn] = i0; idxw[BN_ + bn] = i1; idxw[2 * BN_ + bn] = i2;
    www[bn] = r0 * inv; www[BN_ + bn] = r1 * inv; www[2 * BN_ + bn] = r2 * inv;
  }
}

// ---------------- kernel 3: interpolation -> x panels 16..47 ----------------
__global__ __launch_bounds__(256) void k_interp(const float* __restrict__ p2, const int* __restrict__ idxw,
                                                const float* __restrict__ www, bf16* __restrict__ xp) {
  __shared__ float rows[4][S_];   // 32 KB
  const int b = blockIdx.y;
  const int n = blockIdx.x * 256 + threadIdx.x;
  const int bn = b * N_ + n;
  const int j0 = idxw[bn], j1 = idxw[BN_ + bn], j2 = idxw[2 * BN_ + bn];
  const float w0 = www[bn], w1 = www[BN_ + bn], w2 = www[2 * BN_ + bn];
  const float* src = p2 + (size_t)b * D2_ * S_;
  #pragma unroll 1
  for (int c8 = 0; c8 < 32; ++c8) {
    bf16x8_t out;
    #pragma unroll
    for (int h = 0; h < 2; ++h) {
      __syncthreads();
      const float4* s4 = (const float4*)(src + (size_t)(c8 * 8 + h * 4) * S_);
      float4* r4 = (float4*)rows;
      #pragma unroll
      for (int i = 0; i < 8; ++i) r4[threadIdx.x + i * 256] = s4[threadIdx.x + i * 256];
      __syncthreads();
      #pragma unroll
      for (int j = 0; j < 4; ++j)
        out[h * 4 + j] = (bf16)(w0 * rows[j][j0] + w1 * rows[j][j1] + w2 * rows[j][j2]);
    }
    *(bf16x8_t*)(xp + (((size_t)b * 48 + 16 + c8) * N_ + (size_t)n) * 8) = out;
  }
}

// ---------------- kernel 4: GEMM  Y[b][o][n] = sum_k W[o][k] * X[b][k][n] + bias[o] ----------------
template<int K>
__global__ __launch_bounds__(256) void k_gemm(const float* __restrict__ W, const float* __restrict__ bias,
                                              const bf16* __restrict__ X, float* __restrict__ Y) {
  __shared__ bf16 As[128][40];
  __shared__ bf16 Bt[128][40];
  const int tid = threadIdx.x;
  const int lane = tid & 63, wid = tid >> 6;
  const int wr = wid >> 1, wc = wid & 1;
  const int n0 = blockIdx.x * 128;
  const int m0 = blockIdx.y * 128;
  const int b  = blockIdx.z;
  const int l15 = lane & 15, l4 = lane >> 4;

  f32x4_t acc[4][4];
  #pragma unroll
  for (int i = 0; i < 4; ++i)
    #pragma unroll
    for (int j = 0; j < 4; ++j) { f32x4_t z = {0.f, 0.f, 0.f, 0.f}; acc[i][j] = z; }

  const int arow = tid >> 1, ac0 = (tid & 1) * 16;
  const bf16* Xb = X + (size_t)b * (K / 8) * ((size_t)N_ * 8);

  for (int kt = 0; kt < K; kt += 32) {
    {
      const float* s = W + (size_t)(m0 + arow) * K + kt + ac0;
      const float4 f0 = *(const float4*)(s);
      const float4 f1 = *(const float4*)(s + 4);
      const float4 f2 = *(const float4*)(s + 8);
      const float4 f3 = *(const float4*)(s + 12);
      bf16x8_t h0, h1;
      h0[0] = (bf16)f0.x; h0[1] = (bf16)f0.y; h0[2] = (bf16)f0.z; h0[3] = (bf16)f0.w;
      h0[4] = (bf16)f1.x; h0[5] = (bf16)f1.y; h0[6] = (bf16)f1.z; h0[7] = (bf16)f1.w;
      h1[0] = (bf16)f2.x; h1[1] = (bf16)f2.y; h1[2] = (bf16)f2.z; h1[3] = (bf16)f2.w;
      h1[4] = (bf16)f3.x; h1[5] = (bf16)f3.y; h1[6] = (bf16)f3.z; h1[7] = (bf16)f3.w;
      *(bf16x8_t*)&As[arow][ac0]     = h0;
      *(bf16x8_t*)&As[arow][ac0 + 8] = h1;
    }
    {
      const bf16* s = Xb + ((size_t)(kt / 8 + wid)) * ((size_t)N_ * 8) + (size_t)n0 * 8;
      const bf16x8_t q0 = *(const bf16x8_t*)(s + (size_t)lane * 8);
      const bf16x8_t q1 = *(const bf16x8_t*)(s + (size_t)(lane + 64) * 8);
      *(bf16x8_t*)&Bt[lane][wid * 8]      = q0;
      *(bf16x8_t*)&Bt[lane + 64][wid * 8] = q1;
    }
    __syncthreads();
    bf16x8_t af[4], bfr[4];
    #pragma unroll
    for (int mi = 0; mi < 4; ++mi) af[mi]  = *(const bf16x8_t*)&As[wr * 64 + mi * 16 + l15][l4 * 8];
    #pragma unroll
    for (int ni = 0; ni < 4; ++ni) bfr[ni] = *(const bf16x8_t*)&Bt[wc * 64 + ni * 16 + l15][l4 * 8];
    #pragma unroll
    for (int mi = 0; mi < 4; ++mi)
      #pragma unroll
      for (int ni = 0; ni < 4; ++ni)
        acc[mi][ni] = __builtin_amdgcn_mfma_f32_16x16x32_bf16(af[mi], bfr[ni], acc[mi][ni], 0, 0, 0);
    __syncthreads();
  }
  float* Yb = Y + (size_t)b * O_ * N_;
  #pragma unroll
  for (int mi = 0; mi < 4; ++mi)
    #pragma unroll
    for (int j = 0; j < 4; ++j) {
      const int o = m0 + wr * 64 + mi * 16 + l4 * 4 + j;
      const float bv = bias[o];
      #pragma unroll
      for (int ni = 0; ni < 4; ++ni) {
        const int nn = n0 + wc * 64 + ni * 16 + l15;
        Yb[(size_t)o * N_ + nn] = acc[mi][ni][j] + bv;
      }
    }
}

// ---------------- kernel 5: per-channel BN stats -> scale/shift ----------------
__global__ __launch_bounds__(256) void k_stats(const float* __restrict__ Y, const float* __restrict__ g,
                                               const float* __restrict__ be, float* __restrict__ ss) {
  const int c = blockIdx.x;
  float sum = 0.f, sq = 0.f;
  for (int b = 0; b < B_; ++b) {
    const float4* p = (const float4*)(Y + ((size_t)b * O_ + c) * N_);
    for (int i = threadIdx.x; i < N_ / 4; i += 256) {
      const float4 v = p[i];
      sum += v.x + v.y + v.z + v.w;
      sq = fmaf(v.x, v.x, sq); sq = fmaf(v.y, v.y, sq);
      sq = fmaf(v.z, v.z, sq); sq = fmaf(v.w, v.w, sq);
    }
  }
  #pragma unroll
  for (int off = 32; off; off >>= 1) { sum += __shfl_down(sum, off); sq += __shfl_down(sq, off); }
  __shared__ float w1s[4], w2s[4];
  const int wid = threadIdx.x >> 6;
  if ((threadIdx.x & 63) == 0) { w1s[wid] = sum; w2s[wid] = sq; }
  __syncthreads();
  if (threadIdx.x == 0) {
    const float s = w1s[0] + w1s[1] + w1s[2] + w1s[3];
    const float q = w2s[0] + w2s[1] + w2s[2] + w2s[3];
    const float mean = s * (1.f / 65536.f);
    const float var  = q * (1.f / 65536.f) - mean * mean;
    const float rstd = rsqrtf(var + 1e-5f);
    const float sc = g[c] * rstd;
    ss[c] = sc; ss[O_ + c] = be[c] - mean * sc;
  }
}

// ---------------- kernel 6: z = bf16(relu(y*s+sh)) into panel layout ----------------
__global__ __launch_bounds__(256) void k_apply(const float* __restrict__ Y, const float* __restrict__ ss,
                                               bf16* __restrict__ Z) {
  const int n  = blockIdx.x * 256 + threadIdx.x;
  const int c8 = blockIdx.y;
  const int b  = blockIdx.z;
  bf16x8_t out;
  #pragma unroll
  for (int j = 0; j < 8; ++j) {
    const int c = c8 * 8 + j;
    float v = Y[((size_t)b * O_ + c) * N_ + n];
    v = fmaxf(fmaf(v, ss[c], ss[O_ + c]), 0.f);
    out[j] = (bf16)v;
  }
  *(bf16x8_t*)(Z + (((size_t)b * 32 + c8) * N_ + (size_t)n) * 8) = out;
}

// ---------------- kernel 7: final BN+ReLU in place (fp32) ----------------
__global__ __launch_bounds__(256) void k_final(float* __restrict__ Y, const float* __restrict__ ss) {
  const size_t g = ((size_t)blockIdx.x * 256 + threadIdx.x) * 8;
  const int c = (int)((g >> 13) & 255);
  const float sc = ss[c], sh = ss[O_ + c];
  float4 v0 = *(float4*)(Y + g), v1 = *(float4*)(Y + g + 4);
  v0.x = fmaxf(fmaf(v0.x, sc, sh), 0.f); v0.y = fmaxf(fmaf(v0.y, sc, sh), 0.f);
  v0.z = fmaxf(fmaf(v0.z, sc, sh), 0.f); v0.w = fmaxf(fmaf(v0.w, sc, sh), 0.f);
  v1.x = fmaxf(fmaf(v1.x, sc, sh), 0.f); v1.y = fmaxf(fmaf(v1.y, sc, sh), 0.f);
  v1.z = fmaxf(fmaf(v1.z, sc, sh), 0.f); v1.w = fmaxf(fmaf(v1.w, sc, sh), 0.f);
  *(float4*)(Y + g) = v0; *(float4*)(Y + g + 4) = v1;
}

extern "C" void kernel_launch(void* const* d_in, const int* in_sizes, int n_in,
                              void* d_out, int out_size, void* d_ws, size_t ws_size,
                              hipStream_t stream) {
  const float* xyz1    = (const float*)d_in[0];
  const float* xyz2    = (const float*)d_in[1];
  const float* points1 = (const float*)d_in[2];
  const float* points2 = (const float*)d_in[3];
  const float* W1  = (const float*)d_in[4];
  const float* b1  = (const float*)d_in[5];
  const float* g1  = (const float*)d_in[6];
  const float* be1 = (const float*)d_in[7];
  const float* W2  = (const float*)d_in[8];
  const float* b2  = (const float*)d_in[9];
  const float* g2  = (const float*)d_in[10];
  const float* be2 = (const float*)d_in[11];
  float* Y = (float*)d_out;
  char*  ws = (char*)d_ws;
  int*   idxw = (int*)(ws + OFF_IDX);
  float* www  = (float*)(ws + OFF_W);
  bf16*  xp   = (bf16*)(ws + OFF_XP);
  bf16*  Z    = (bf16*)(ws + OFF_Z);
  float* ss1  = (float*)(ws + OFF_SS1);
  float* ss2  = (float*)(ws + OFF_SS2);

  hipLaunchKernelGGL(k_conv_p1, dim3(1024), dim3(256), 0, stream, points1, xp);
  hipLaunchKernelGGL(k_nn3, dim3(64, 8), dim3(256), 0, stream, xyz1, xyz2, idxw, www);
  hipLaunchKernelGGL(k_interp, dim3(32, 8), dim3(256), 0, stream, points2, idxw, www, xp);
  hipLaunchKernelGGL((k_gemm<384>), dim3(64, 2, 8), dim3(256), 0, stream, W1, b1, xp, Y);
  hipLaunchKernelGGL(k_stats, dim3(256), dim3(256), 0, stream, Y, g1, be1, ss1);
  hipLaunchKernelGGL(k_apply, dim3(32, 32, 8), dim3(256), 0, stream, Y, ss1, Z);
  hipLaunchKernelGGL((k_gemm<256>), dim3(64, 2, 8), dim3(256), 0, stream, W2, b2, Z, Y);
  hipLaunchKernelGGL(k_stats, dim3(256), dim3(256), 0, stream, Y, g2, be2, ss2);
  hipLaunchKernelGGL(k_final, dim3(8192), dim3(256), 0, stream, Y, ss2);
}

// Round 3
// 244.792 us; speedup vs baseline: 1.2502x; 1.1307x over previous
//
#include <hip/hip_runtime.h>

#define B_   8
#define N_   8192
#define S_   2048
#define D1_  128
#define D2_  256
#define C1_  384
#define O_   256
#define BN_  (B_*N_)   // 65536

typedef __bf16 bf16;
typedef __bf16 bf16x8_t __attribute__((ext_vector_type(8)));
typedef float  f32x4_t  __attribute__((ext_vector_type(4)));

// ---------------- workspace layout ----------------
static const size_t OFF_IDX = 0;
static const size_t OFF_W   = 786432;
static const size_t OFF_XP  = 1572864;
static const size_t OFF_Z   = 51904512;   // Z panels (apply->gemm2); f2t aliases here (t2->interp2)
static const size_t OFF_SS1 = 85458944;
static const size_t OFF_SS2 = 85460992;

// ---------------- kernel 1: points1 -> x panels 0..15 (bf16, [B][48][N][8]) ----------------
__global__ __launch_bounds__(256) void k_conv_p1(const float* __restrict__ p1, bf16* __restrict__ xp) {
  const int g  = blockIdx.x * 256 + threadIdx.x;
  const int n4 = g & 2047;
  const int c8 = (g >> 11) & 15;
  const int b  = g >> 15;
  const int n  = n4 * 4;
  const float* src = p1 + ((size_t)b * D1_ + c8 * 8) * N_ + n;
  bf16x8_t o0, o1, o2, o3;
  #pragma unroll
  for (int j = 0; j < 8; ++j) {
    float4 v = *(const float4*)(src + (size_t)j * N_);
    o0[j] = (bf16)v.x; o1[j] = (bf16)v.y; o2[j] = (bf16)v.z; o3[j] = (bf16)v.w;
  }
  bf16* dst = xp + (((size_t)b * 48 + c8) * N_ + n) * 8;
  *(bf16x8_t*)(dst)      = o0;
  *(bf16x8_t*)(dst + 8)  = o1;
  *(bf16x8_t*)(dst + 16) = o2;
  *(bf16x8_t*)(dst + 24) = o3;
}

// ---------------- kernel 2: 3-NN search (branchless, 2 pts/thread, 4 S-chunks/block) ----------
__device__ __forceinline__ void ins3(float d, int i,
                                     float& d0, float& d1, float& d2,
                                     int& i0, int& i1, int& i2) {
  const bool c2 = d < d2, c1 = d < d1, c0 = d < d0;
  const float nd2 = c1 ? d1 : (c2 ? d : d2); const int ni2 = c1 ? i1 : (c2 ? i : i2);
  const float nd1 = c0 ? d0 : (c1 ? d : d1); const int ni1 = c0 ? i0 : (c1 ? i : i1);
  d0 = c0 ? d : d0; i0 = c0 ? i : i0;
  d1 = nd1; i1 = ni1; d2 = nd2; i2 = ni2;
}

#define INS_BL(E, SI, e0, e1, e2, i0, i1, i2)            \
  {                                                      \
    const bool l0 = (E) < e0, l1 = (E) < e1, l2 = (E) < e2; \
    const int  t1 = l0 ? i0 : (l1 ? (SI) : i1);          \
    const int  t2 = l1 ? i1 : (l2 ? (SI) : i2);          \
    i0 = l0 ? (SI) : i0; i1 = t1; i2 = t2;               \
    const float m1 = fminf(fmaxf((E), e0), e1);          \
    const float m2 = fminf(fmaxf((E), e1), e2);          \
    e0 = fminf((E), e0); e1 = m1; e2 = m2;               \
  }

__global__ __launch_bounds__(256) void k_nn3(const float* __restrict__ xyz1, const float* __restrict__ xyz2,
                                             int* __restrict__ idxw, float* __restrict__ www) {
  __shared__ float4 sq[4][S_ / 4];
  __shared__ float  pd[4][128][3];
  __shared__ int    pi[4][128][3];
  const int tid  = threadIdx.x;
  const int lane = tid & 63, w = tid >> 6;
  const int b     = blockIdx.y;
  const int nbase = blockIdx.x * 128;

  const float* x2 = xyz2 + (size_t)b * 3 * S_;
  for (int j = tid; j < S_ / 4; j += 256) {
    const float4 x = *(const float4*)(x2 + 4 * j);
    const float4 y = *(const float4*)(x2 + S_ + 4 * j);
    const float4 z = *(const float4*)(x2 + 2 * S_ + 4 * j);
    float4 qq;
    qq.x = fmaf(x.x, x.x, fmaf(y.x, y.x, z.x * z.x));
    qq.y = fmaf(x.y, x.y, fmaf(y.y, y.y, z.y * z.y));
    qq.z = fmaf(x.z, x.z, fmaf(y.z, y.z, z.z * z.z));
    qq.w = fmaf(x.w, x.w, fmaf(y.w, y.w, z.w * z.w));
    sq[0][j] = x; sq[1][j] = y; sq[2][j] = z; sq[3][j] = qq;
  }

  const int n_a = nbase + lane, n_b = n_a + 64;
  const float* x1 = xyz1 + (size_t)b * 3 * N_;
  const float pax = x1[n_a], pay = x1[N_ + n_a], paz = x1[2 * N_ + n_a];
  const float pbx = x1[n_b], pby = x1[N_ + n_b], pbz = x1[2 * N_ + n_b];
  const float ax = -2.f * pax, ay = -2.f * pay, az = -2.f * paz;
  const float bx = -2.f * pbx, by = -2.f * pby, bz = -2.f * pbz;
  __syncthreads();

  float ea0 = 3.4e38f, ea1 = 3.4e38f, ea2 = 3.4e38f;
  float eb0 = 3.4e38f, eb1 = 3.4e38f, eb2 = 3.4e38f;
  int ia0 = 0, ia1 = 0, ia2 = 0, ib0 = 0, ib1 = 0, ib2 = 0;

  const int jb = w * (S_ / 16);
  #pragma unroll 2
  for (int j = jb; j < jb + S_ / 16; ++j) {
    const float4 qx = sq[0][j], qy = sq[1][j], qz = sq[2][j], qq = sq[3][j];
    #define CAND(C, SI)                                                    \
      {                                                                    \
        const float Ea = fmaf(ax, qx.C, fmaf(ay, qy.C, fmaf(az, qz.C, qq.C))); \
        const float Eb = fmaf(bx, qx.C, fmaf(by, qy.C, fmaf(bz, qz.C, qq.C))); \
        INS_BL(Ea, SI, ea0, ea1, ea2, ia0, ia1, ia2);                      \
        INS_BL(Eb, SI, eb0, eb1, eb2, ib0, ib1, ib2);                      \
      }
    CAND(x, 4 * j + 0)
    CAND(y, 4 * j + 1)
    CAND(z, 4 * j + 2)
    CAND(w, 4 * j + 3)
    #undef CAND
  }

  const float ppa = fmaf(pax, pax, fmaf(pay, pay, paz * paz));
  const float ppb = fmaf(pbx, pbx, fmaf(pby, pby, pbz * pbz));
  pd[w][lane][0] = ea0 + ppa; pd[w][lane][1] = ea1 + ppa; pd[w][lane][2] = ea2 + ppa;
  pi[w][lane][0] = ia0; pi[w][lane][1] = ia1; pi[w][lane][2] = ia2;
  pd[w][lane + 64][0] = eb0 + ppb; pd[w][lane + 64][1] = eb1 + ppb; pd[w][lane + 64][2] = eb2 + ppb;
  pi[w][lane + 64][0] = ib0; pi[w][lane + 64][1] = ib1; pi[w][lane + 64][2] = ib2;
  __syncthreads();

  if (tid < 128) {
    float d0 = pd[0][tid][0], d1 = pd[0][tid][1], d2 = pd[0][tid][2];
    int   i0 = pi[0][tid][0], i1 = pi[0][tid][1], i2 = pi[0][tid][2];
    #pragma unroll
    for (int ck = 1; ck < 4; ++ck)
      #pragma unroll
      for (int k = 0; k < 3; ++k)
        ins3(pd[ck][tid][k], pi[ck][tid][k], d0, d1, d2, i0, i1, i2);
    const float r0 = 1.f / (d0 + 1e-8f), r1 = 1.f / (d1 + 1e-8f), r2 = 1.f / (d2 + 1e-8f);
    const float inv = 1.f / (r0 + r1 + r2);
    const int bn = b * N_ + nbase + tid;
    idxw[bn] = i0; idxw[BN_ + bn] = i1; idxw[2 * BN_ + bn] = i2;
    www[bn] = r0 * inv; www[BN_ + bn] = r1 * inv; www[2 * BN_ + bn] = r2 * inv;
  }
}

// ---------------- kernel 3a: transpose points2 (B,256,2048) f32 -> f2t (B,2048,256) bf16 ------
// grid 1024: b = bid&7 (XCD-resident per batch), inner = bid>>3: s_tile(32) x c_tile(4)
__global__ __launch_bounds__(256) void k_t2(const float* __restrict__ p2, bf16* __restrict__ f2t) {
  __shared__ float lds[64][65];
  const int bid = blockIdx.x;
  const int b = bid & 7;
  const int inner = bid >> 3;
  const int s0 = (inner & 31) * 64;
  const int c0 = (inner >> 5) * 64;
  const int t = threadIdx.x;
  // read: 64 c-rows x 64 s; thread: cr = t>>2, 16 floats at (t&3)*16
  {
    const int cr = t >> 2, scb = (t & 3) * 16;
    const float* src = p2 + ((size_t)b * D2_ + c0 + cr) * S_ + s0 + scb;
    #pragma unroll
    for (int i = 0; i < 4; ++i) {
      const float4 v = *(const float4*)(src + 4 * i);
      lds[cr][scb + 4 * i + 0] = v.x; lds[cr][scb + 4 * i + 1] = v.y;
      lds[cr][scb + 4 * i + 2] = v.z; lds[cr][scb + 4 * i + 3] = v.w;
    }
  }
  __syncthreads();
  // write: 64 s-rows x 64 c bf16; thread: s = pass*32 + t>>3, c chunk (t&7)*8
  const int co = (t & 7) * 8;
  #pragma unroll
  for (int pass = 0; pass < 2; ++pass) {
    const int s = pass * 32 + (t >> 3);
    bf16x8_t o;
    #pragma unroll
    for (int j = 0; j < 8; ++j) o[j] = (bf16)lds[co + j][s];
    *(bf16x8_t*)(f2t + ((size_t)b * S_ + s0 + s) * D2_ + c0 + co) = o;
  }
}

// ---------------- kernel 3b: gather-interp -> x panels 16..47 ----------------
// grid 8192: b = bid&7 (matches k_t2 XCD residency), n0 = (bid>>3)*8
// thread: n_off = t&7, c8 = t>>3
__global__ __launch_bounds__(256) void k_interp(const bf16* __restrict__ f2t, const int* __restrict__ idxw,
                                                const float* __restrict__ www, bf16* __restrict__ xp) {
  const int bid = blockIdx.x;
  const int b = bid & 7;
  const int n = (bid >> 3) * 8 + (threadIdx.x & 7);
  const int c8 = threadIdx.x >> 3;
  const int bn = b * N_ + n;
  const int j0 = idxw[bn], j1 = idxw[BN_ + bn], j2 = idxw[2 * BN_ + bn];
  const float w0 = www[bn], w1 = www[BN_ + bn], w2 = www[2 * BN_ + bn];
  const bf16* base = f2t + (size_t)b * S_ * D2_ + c8 * 8;
  const bf16x8_t v0 = *(const bf16x8_t*)(base + (size_t)j0 * D2_);
  const bf16x8_t v1 = *(const bf16x8_t*)(base + (size_t)j1 * D2_);
  const bf16x8_t v2 = *(const bf16x8_t*)(base + (size_t)j2 * D2_);
  bf16x8_t out;
  #pragma unroll
  for (int j = 0; j < 8; ++j)
    out[j] = (bf16)(w0 * (float)v0[j] + w1 * (float)v1[j] + w2 * (float)v2[j]);
  *(bf16x8_t*)(xp + (((size_t)b * 48 + 16 + c8) * N_ + (size_t)n) * 8) = out;
}

// ---------------- kernel 4: GEMM  Y[b][o][n] = sum_k W[o][k] * X[b][k][n] + bias[o] ----------------
template<int K>
__global__ __launch_bounds__(256) void k_gemm(const float* __restrict__ W, const float* __restrict__ bias,
                                              const bf16* __restrict__ X, float* __restrict__ Y) {
  __shared__ bf16 As[128][40];
  __shared__ bf16 Bt[128][40];
  const int tid = threadIdx.x;
  const int lane = tid & 63, wid = tid >> 6;
  const int wr = wid >> 1, wc = wid & 1;
  const int n0 = blockIdx.x * 128;
  const int m0 = blockIdx.y * 128;
  const int b  = blockIdx.z;
  const int l15 = lane & 15, l4 = lane >> 4;

  f32x4_t acc[4][4];
  #pragma unroll
  for (int i = 0; i < 4; ++i)
    #pragma unroll
    for (int j = 0; j < 4; ++j) { f32x4_t z = {0.f, 0.f, 0.f, 0.f}; acc[i][j] = z; }

  const int arow = tid >> 1, ac0 = (tid & 1) * 16;
  const bf16* Xb = X + (size_t)b * (K / 8) * ((size_t)N_ * 8);

  for (int kt = 0; kt < K; kt += 32) {
    {
      const float* s = W + (size_t)(m0 + arow) * K + kt + ac0;
      const float4 f0 = *(const float4*)(s);
      const float4 f1 = *(const float4*)(s + 4);
      const float4 f2 = *(const float4*)(s + 8);
      const float4 f3 = *(const float4*)(s + 12);
      bf16x8_t h0, h1;
      h0[0] = (bf16)f0.x; h0[1] = (bf16)f0.y; h0[2] = (bf16)f0.z; h0[3] = (bf16)f0.w;
      h0[4] = (bf16)f1.x; h0[5] = (bf16)f1.y; h0[6] = (bf16)f1.z; h0[7] = (bf16)f1.w;
      h1[0] = (bf16)f2.x; h1[1] = (bf16)f2.y; h1[2] = (bf16)f2.z; h1[3] = (bf16)f2.w;
      h1[4] = (bf16)f3.x; h1[5] = (bf16)f3.y; h1[6] = (bf16)f3.z; h1[7] = (bf16)f3.w;
      *(bf16x8_t*)&As[arow][ac0]     = h0;
      *(bf16x8_t*)&As[arow][ac0 + 8] = h1;
    }
    {
      const bf16* s = Xb + ((size_t)(kt / 8 + wid)) * ((size_t)N_ * 8) + (size_t)n0 * 8;
      const bf16x8_t q0 = *(const bf16x8_t*)(s + (size_t)lane * 8);
      const bf16x8_t q1 = *(const bf16x8_t*)(s + (size_t)(lane + 64) * 8);
      *(bf16x8_t*)&Bt[lane][wid * 8]      = q0;
      *(bf16x8_t*)&Bt[lane + 64][wid * 8] = q1;
    }
    __syncthreads();
    bf16x8_t af[4], bfr[4];
    #pragma unroll
    for (int mi = 0; mi < 4; ++mi) af[mi]  = *(const bf16x8_t*)&As[wr * 64 + mi * 16 + l15][l4 * 8];
    #pragma unroll
    for (int ni = 0; ni < 4; ++ni) bfr[ni] = *(const bf16x8_t*)&Bt[wc * 64 + ni * 16 + l15][l4 * 8];
    #pragma unroll
    for (int mi = 0; mi < 4; ++mi)
      #pragma unroll
      for (int ni = 0; ni < 4; ++ni)
        acc[mi][ni] = __builtin_amdgcn_mfma_f32_16x16x32_bf16(af[mi], bfr[ni], acc[mi][ni], 0, 0, 0);
    __syncthreads();
  }
  float* Yb = Y + (size_t)b * O_ * N_;
  #pragma unroll
  for (int mi = 0; mi < 4; ++mi)
    #pragma unroll
    for (int j = 0; j < 4; ++j) {
      const int o = m0 + wr * 64 + mi * 16 + l4 * 4 + j;
      const float bv = bias[o];
      #pragma unroll
      for (int ni = 0; ni < 4; ++ni) {
        const int nn = n0 + wc * 64 + ni * 16 + l15;
        Yb[(size_t)o * N_ + nn] = acc[mi][ni][j] + bv;
      }
    }
}

// ---------------- kernel 5: per-channel BN stats -> scale/shift ----------------
__global__ __launch_bounds__(256) void k_stats(const float* __restrict__ Y, const float* __restrict__ g,
                                               const float* __restrict__ be, float* __restrict__ ss) {
  const int c = blockIdx.x;
  float sum = 0.f, sq = 0.f;
  for (int b = 0; b < B_; ++b) {
    const float4* p = (const float4*)(Y + ((size_t)b * O_ + c) * N_);
    for (int i = threadIdx.x; i < N_ / 4; i += 256) {
      const float4 v = p[i];
      sum += v.x + v.y + v.z + v.w;
      sq = fmaf(v.x, v.x, sq); sq = fmaf(v.y, v.y, sq);
      sq = fmaf(v.z, v.z, sq); sq = fmaf(v.w, v.w, sq);
    }
  }
  #pragma unroll
  for (int off = 32; off; off >>= 1) { sum += __shfl_down(sum, off); sq += __shfl_down(sq, off); }
  __shared__ float w1s[4], w2s[4];
  const int wid = threadIdx.x >> 6;
  if ((threadIdx.x & 63) == 0) { w1s[wid] = sum; w2s[wid] = sq; }
  __syncthreads();
  if (threadIdx.x == 0) {
    const float s = w1s[0] + w1s[1] + w1s[2] + w1s[3];
    const float q = w2s[0] + w2s[1] + w2s[2] + w2s[3];
    const float mean = s * (1.f / 65536.f);
    const float var  = q * (1.f / 65536.f) - mean * mean;
    const float rstd = rsqrtf(var + 1e-5f);
    const float sc = g[c] * rstd;
    ss[c] = sc; ss[O_ + c] = be[c] - mean * sc;
  }
}

// ---------------- kernel 6: z = bf16(relu(y*s+sh)) into panel layout ----------------
__global__ __launch_bounds__(256) void k_apply(const float* __restrict__ Y, const float* __restrict__ ss,
                                               bf16* __restrict__ Z) {
  const int n  = blockIdx.x * 256 + threadIdx.x;
  const int c8 = blockIdx.y;
  const int b  = blockIdx.z;
  bf16x8_t out;
  #pragma unroll
  for (int j = 0; j < 8; ++j) {
    const int c = c8 * 8 + j;
    float v = Y[((size_t)b * O_ + c) * N_ + n];
    v = fmaxf(fmaf(v, ss[c], ss[O_ + c]), 0.f);
    out[j] = (bf16)v;
  }
  *(bf16x8_t*)(Z + (((size_t)b * 32 + c8) * N_ + (size_t)n) * 8) = out;
}

// ---------------- kernel 7: final BN+ReLU in place (fp32) ----------------
__global__ __launch_bounds__(256) void k_final(float* __restrict__ Y, const float* __restrict__ ss) {
  const size_t g = ((size_t)blockIdx.x * 256 + threadIdx.x) * 8;
  const int c = (int)((g >> 13) & 255);
  const float sc = ss[c], sh = ss[O_ + c];
  float4 v0 = *(float4*)(Y + g), v1 = *(float4*)(Y + g + 4);
  v0.x = fmaxf(fmaf(v0.x, sc, sh), 0.f); v0.y = fmaxf(fmaf(v0.y, sc, sh), 0.f);
  v0.z = fmaxf(fmaf(v0.z, sc, sh), 0.f); v0.w = fmaxf(fmaf(v0.w, sc, sh), 0.f);
  v1.x = fmaxf(fmaf(v1.x, sc, sh), 0.f); v1.y = fmaxf(fmaf(v1.y, sc, sh), 0.f);
  v1.z = fmaxf(fmaf(v1.z, sc, sh), 0.f); v1.w = fmaxf(fmaf(v1.w, sc, sh), 0.f);
  *(float4*)(Y + g) = v0; *(float4*)(Y + g + 4) = v1;
}

extern "C" void kernel_launch(void* const* d_in, const int* in_sizes, int n_in,
                              void* d_out, int out_size, void* d_ws, size_t ws_size,
                              hipStream_t stream) {
  const float* xyz1    = (const float*)d_in[0];
  const float* xyz2    = (const float*)d_in[1];
  const float* points1 = (const float*)d_in[2];
  const float* points2 = (const float*)d_in[3];
  const float* W1  = (const float*)d_in[4];
  const float* b1  = (const float*)d_in[5];
  const float* g1  = (const float*)d_in[6];
  const float* be1 = (const float*)d_in[7];
  const float* W2  = (const float*)d_in[8];
  const float* b2  = (const float*)d_in[9];
  const float* g2  = (const float*)d_in[10];
  const float* be2 = (const float*)d_in[11];
  float* Y = (float*)d_out;
  char*  ws = (char*)d_ws;
  int*   idxw = (int*)(ws + OFF_IDX);
  float* www  = (float*)(ws + OFF_W);
  bf16*  xp   = (bf16*)(ws + OFF_XP);
  bf16*  Z    = (bf16*)(ws + OFF_Z);
  bf16*  f2t  = (bf16*)(ws + OFF_Z);   // aliases Z: lifetimes disjoint
  float* ss1  = (float*)(ws + OFF_SS1);
  float* ss2  = (float*)(ws + OFF_SS2);

  hipLaunchKernelGGL(k_conv_p1, dim3(1024), dim3(256), 0, stream, points1, xp);
  hipLaunchKernelGGL(k_nn3, dim3(64, 8), dim3(256), 0, stream, xyz1, xyz2, idxw, www);
  hipLaunchKernelGGL(k_t2, dim3(1024), dim3(256), 0, stream, points2, f2t);
  hipLaunchKernelGGL(k_interp, dim3(8192), dim3(256), 0, stream, f2t, idxw, www, xp);
  hipLaunchKernelGGL((k_gemm<384>), dim3(64, 2, 8), dim3(256), 0, stream, W1, b1, xp, Y);
  hipLaunchKernelGGL(k_stats, dim3(256), dim3(256), 0, stream, Y, g1, be1, ss1);
  hipLaunchKernelGGL(k_apply, dim3(32, 32, 8), dim3(256), 0, stream, Y, ss1, Z);
  hipLaunchKernelGGL((k_gemm<256>), dim3(64, 2, 8), dim3(256), 0, stream, W2, b2, Z, Y);
  hipLaunchKernelGGL(k_stats, dim3(256), dim3(256), 0, stream, Y, g2, be2, ss2);
  hipLaunchKernelGGL(k_final, dim3(8192), dim3(256), 0, stream, Y, ss2);
}

// Round 4
// 196.394 us; speedup vs baseline: 1.5583x; 1.2464x over previous
//
#include <hip/hip_runtime.h>

#define B_   8
#define N_   8192
#define S_   2048
#define D1_  128
#define D2_  256
#define O_   256
#define BN_  (B_*N_)   // 65536

typedef __bf16 bf16;
typedef __bf16 bf16x8_t __attribute__((ext_vector_type(8)));
typedef __bf16 bf16x4_t __attribute__((ext_vector_type(4)));
typedef float  f32x4_t  __attribute__((ext_vector_type(4)));

// ---------------- workspace layout ----------------
// idx: 786432 | w: 786432 | xp panels [B][48][N][8] bf16 = 50331648 (z2 aliases)
// OFF_Z 33554432: f2t (t2->interp), then z1 panels [B][32][N][8] (gemm1->gemm2)
// ss1/ss2: 2KB each | part: 16KB
static const size_t OFF_IDX  = 0;
static const size_t OFF_W    = 786432;
static const size_t OFF_XP   = 1572864;
static const size_t OFF_Z    = 51904512;
static const size_t OFF_SS1  = 85458944;
static const size_t OFF_SS2  = 85460992;
static const size_t OFF_PART = 85463040;

// ---------------- kernel 1: points1 -> x panels 0..15 (bf16, [B][48][N][8]) ----------------
__global__ __launch_bounds__(256) void k_conv_p1(const float* __restrict__ p1, bf16* __restrict__ xp) {
  const int g  = blockIdx.x * 256 + threadIdx.x;
  const int n4 = g & 2047;
  const int c8 = (g >> 11) & 15;
  const int b  = g >> 15;
  const int n  = n4 * 4;
  const float* src = p1 + ((size_t)b * D1_ + c8 * 8) * N_ + n;
  bf16x8_t o0, o1, o2, o3;
  #pragma unroll
  for (int j = 0; j < 8; ++j) {
    float4 v = *(const float4*)(src + (size_t)j * N_);
    o0[j] = (bf16)v.x; o1[j] = (bf16)v.y; o2[j] = (bf16)v.z; o3[j] = (bf16)v.w;
  }
  bf16* dst = xp + (((size_t)b * 48 + c8) * N_ + n) * 8;
  *(bf16x8_t*)(dst)      = o0;
  *(bf16x8_t*)(dst + 8)  = o1;
  *(bf16x8_t*)(dst + 16) = o2;
  *(bf16x8_t*)(dst + 24) = o3;
}

// ---------------- kernel 2: 3-NN search v3 (1 pt/thread, med3 insert, 4 S-chunks) ----------
__device__ __forceinline__ void ins3(float d, int i,
                                     float& d0, float& d1, float& d2,
                                     int& i0, int& i1, int& i2) {
  const bool c2 = d < d2, c1 = d < d1, c0 = d < d0;
  const float nd2 = c1 ? d1 : (c2 ? d : d2); const int ni2 = c1 ? i1 : (c2 ? i : i2);
  const float nd1 = c0 ? d0 : (c1 ? d : d1); const int ni1 = c0 ? i0 : (c1 ? i : i1);
  d0 = c0 ? d : d0; i0 = c0 ? i : i0;
  d1 = nd1; i1 = ni1; d2 = nd2; i2 = ni2;
}

__global__ __launch_bounds__(256) void k_nn3(const float* __restrict__ xyz1, const float* __restrict__ xyz2,
                                             int* __restrict__ idxw, float* __restrict__ www) {
  __shared__ float4 sq[4][S_ / 4];   // x,y,z,|q|^2 planes (32 KB)
  __shared__ float  pd[4][64][3];
  __shared__ int    pi[4][64][3];
  const int tid  = threadIdx.x;
  const int lane = tid & 63, w = tid >> 6;     // w = S-chunk 0..3
  const int b     = blockIdx.y;
  const int nbase = blockIdx.x * 64;

  const float* x2 = xyz2 + (size_t)b * 3 * S_;
  for (int j = tid; j < S_ / 4; j += 256) {
    const float4 x = *(const float4*)(x2 + 4 * j);
    const float4 y = *(const float4*)(x2 + S_ + 4 * j);
    const float4 z = *(const float4*)(x2 + 2 * S_ + 4 * j);
    float4 qq;
    qq.x = fmaf(x.x, x.x, fmaf(y.x, y.x, z.x * z.x));
    qq.y = fmaf(x.y, x.y, fmaf(y.y, y.y, z.y * z.y));
    qq.z = fmaf(x.z, x.z, fmaf(y.z, y.z, z.z * z.z));
    qq.w = fmaf(x.w, x.w, fmaf(y.w, y.w, z.w * z.w));
    sq[0][j] = x; sq[1][j] = y; sq[2][j] = z; sq[3][j] = qq;
  }

  const int n = nbase + lane;
  const float* x1 = xyz1 + (size_t)b * 3 * N_;
  const float px = x1[n], py = x1[N_ + n], pz = x1[2 * N_ + n];
  const float ax = -2.f * px, ay = -2.f * py, az = -2.f * pz;
  __syncthreads();

  float e0 = 3.4e38f, e1 = 3.4e38f, e2 = 3.4e38f;
  int   i0 = 0, i1 = 0, i2 = 0;

  const int jb = w * (S_ / 16);    // 128 float4 groups per chunk
  #pragma unroll 4
  for (int j = jb; j < jb + S_ / 16; ++j) {
    const float4 qx = sq[0][j], qy = sq[1][j], qz = sq[2][j], qq = sq[3][j];
    #define CAND(C, SI)                                                        \
      {                                                                        \
        const float E = fmaf(ax, qx.C, fmaf(ay, qy.C, fmaf(az, qz.C, qq.C))); \
        const bool l0 = E < e0, l1 = E < e1, l2 = E < e2;                      \
        const int ni1 = l0 ? i0 : (l1 ? (SI) : i1);                            \
        const int ni2 = l1 ? i1 : (l2 ? (SI) : i2);                            \
        i0 = l0 ? (SI) : i0; i1 = ni1; i2 = ni2;                               \
        const float ne1 = __builtin_amdgcn_fmed3f(E, e0, e1);                  \
        const float ne2 = __builtin_amdgcn_fmed3f(E, e1, e2);                  \
        e0 = fminf(E, e0); e1 = ne1; e2 = ne2;                                 \
      }
    CAND(x, 4 * j + 0)
    CAND(y, 4 * j + 1)
    CAND(z, 4 * j + 2)
    CAND(w, 4 * j + 3)
    #undef CAND
  }

  const float pp = fmaf(px, px, fmaf(py, py, pz * pz));
  pd[w][lane][0] = e0 + pp; pd[w][lane][1] = e1 + pp; pd[w][lane][2] = e2 + pp;
  pi[w][lane][0] = i0; pi[w][lane][1] = i1; pi[w][lane][2] = i2;
  __syncthreads();

  if (tid < 64) {
    float d0 = pd[0][tid][0], d1 = pd[0][tid][1], d2 = pd[0][tid][2];
    int   j0 = pi[0][tid][0], j1 = pi[0][tid][1], j2 = pi[0][tid][2];
    #pragma unroll
    for (int ck = 1; ck < 4; ++ck)
      #pragma unroll
      for (int k = 0; k < 3; ++k)
        ins3(pd[ck][tid][k], pi[ck][tid][k], d0, d1, d2, j0, j1, j2);
    const float r0 = 1.f / (d0 + 1e-8f), r1 = 1.f / (d1 + 1e-8f), r2 = 1.f / (d2 + 1e-8f);
    const float inv = 1.f / (r0 + r1 + r2);
    const int bn = b * N_ + nbase + tid;
    idxw[bn] = j0; idxw[BN_ + bn] = j1; idxw[2 * BN_ + bn] = j2;
    www[bn] = r0 * inv; www[BN_ + bn] = r1 * inv; www[2 * BN_ + bn] = r2 * inv;
  }
}

// ---------------- kernel 3a: transpose points2 (B,256,2048) f32 -> f2t (B,2048,256) bf16 ------
__global__ __launch_bounds__(256) void k_t2(const float* __restrict__ p2, bf16* __restrict__ f2t) {
  __shared__ float lds[64][65];
  const int bid = blockIdx.x;
  const int b = bid & 7;
  const int inner = bid >> 3;
  const int s0 = (inner & 31) * 64;
  const int c0 = (inner >> 5) * 64;
  const int t = threadIdx.x;
  {
    const int cr = t >> 2, scb = (t & 3) * 16;
    const float* src = p2 + ((size_t)b * D2_ + c0 + cr) * S_ + s0 + scb;
    #pragma unroll
    for (int i = 0; i < 4; ++i) {
      const float4 v = *(const float4*)(src + 4 * i);
      lds[cr][scb + 4 * i + 0] = v.x; lds[cr][scb + 4 * i + 1] = v.y;
      lds[cr][scb + 4 * i + 2] = v.z; lds[cr][scb + 4 * i + 3] = v.w;
    }
  }
  __syncthreads();
  const int co = (t & 7) * 8;
  #pragma unroll
  for (int pass = 0; pass < 2; ++pass) {
    const int s = pass * 32 + (t >> 3);
    bf16x8_t o;
    #pragma unroll
    for (int j = 0; j < 8; ++j) o[j] = (bf16)lds[co + j][s];
    *(bf16x8_t*)(f2t + ((size_t)b * S_ + s0 + s) * D2_ + c0 + co) = o;
  }
}

// ---------------- kernel 3b: gather-interp -> x panels 16..47 ----------------
__global__ __launch_bounds__(256) void k_interp(const bf16* __restrict__ f2t, const int* __restrict__ idxw,
                                                const float* __restrict__ www, bf16* __restrict__ xp) {
  const int bid = blockIdx.x;
  const int b = bid & 7;
  const int n = (bid >> 3) * 8 + (threadIdx.x & 7);
  const int c8 = threadIdx.x >> 3;
  const int bn = b * N_ + n;
  const int j0 = idxw[bn], j1 = idxw[BN_ + bn], j2 = idxw[2 * BN_ + bn];
  const float w0 = www[bn], w1 = www[BN_ + bn], w2 = www[2 * BN_ + bn];
  const bf16* base = f2t + (size_t)b * S_ * D2_ + c8 * 8;
  const bf16x8_t v0 = *(const bf16x8_t*)(base + (size_t)j0 * D2_);
  const bf16x8_t v1 = *(const bf16x8_t*)(base + (size_t)j1 * D2_);
  const bf16x8_t v2 = *(const bf16x8_t*)(base + (size_t)j2 * D2_);
  bf16x8_t out;
  #pragma unroll
  for (int j = 0; j < 8; ++j)
    out[j] = (bf16)(w0 * (float)v0[j] + w1 * (float)v1[j] + w2 * (float)v2[j]);
  *(bf16x8_t*)(xp + (((size_t)b * 48 + 16 + c8) * N_ + (size_t)n) * 8) = out;
}

// ---------------- kernel 4: GEMM -> bf16 panels  Z[b][o/8][n][o%8] = y+bias ----------------
template<int K>
__global__ __launch_bounds__(256) void k_gemm(const float* __restrict__ W, const float* __restrict__ bias,
                                              const bf16* __restrict__ X, bf16* __restrict__ Zp) {
  __shared__ bf16 As[128][40];
  __shared__ bf16 Bt[128][40];
  const int tid = threadIdx.x;
  const int lane = tid & 63, wid = tid >> 6;
  const int wr = wid >> 1, wc = wid & 1;
  const int n0 = blockIdx.x * 128;
  const int m0 = blockIdx.y * 128;
  const int b  = blockIdx.z;
  const int l15 = lane & 15, l4 = lane >> 4;

  f32x4_t acc[4][4];
  #pragma unroll
  for (int i = 0; i < 4; ++i)
    #pragma unroll
    for (int j = 0; j < 4; ++j) { f32x4_t z = {0.f, 0.f, 0.f, 0.f}; acc[i][j] = z; }

  const int arow = tid >> 1, ac0 = (tid & 1) * 16;
  const bf16* Xb = X + (size_t)b * (K / 8) * ((size_t)N_ * 8);

  for (int kt = 0; kt < K; kt += 32) {
    {
      const float* s = W + (size_t)(m0 + arow) * K + kt + ac0;
      const float4 f0 = *(const float4*)(s);
      const float4 f1 = *(const float4*)(s + 4);
      const float4 f2 = *(const float4*)(s + 8);
      const float4 f3 = *(const float4*)(s + 12);
      bf16x8_t h0, h1;
      h0[0] = (bf16)f0.x; h0[1] = (bf16)f0.y; h0[2] = (bf16)f0.z; h0[3] = (bf16)f0.w;
      h0[4] = (bf16)f1.x; h0[5] = (bf16)f1.y; h0[6] = (bf16)f1.z; h0[7] = (bf16)f1.w;
      h1[0] = (bf16)f2.x; h1[1] = (bf16)f2.y; h1[2] = (bf16)f2.z; h1[3] = (bf16)f2.w;
      h1[4] = (bf16)f3.x; h1[5] = (bf16)f3.y; h1[6] = (bf16)f3.z; h1[7] = (bf16)f3.w;
      *(bf16x8_t*)&As[arow][ac0]     = h0;
      *(bf16x8_t*)&As[arow][ac0 + 8] = h1;
    }
    {
      const bf16* s = Xb + ((size_t)(kt / 8 + wid)) * ((size_t)N_ * 8) + (size_t)n0 * 8;
      const bf16x8_t q0 = *(const bf16x8_t*)(s + (size_t)lane * 8);
      const bf16x8_t q1 = *(const bf16x8_t*)(s + (size_t)(lane + 64) * 8);
      *(bf16x8_t*)&Bt[lane][wid * 8]      = q0;
      *(bf16x8_t*)&Bt[lane + 64][wid * 8] = q1;
    }
    __syncthreads();
    bf16x8_t af[4], bfr[4];
    #pragma unroll
    for (int mi = 0; mi < 4; ++mi) af[mi]  = *(const bf16x8_t*)&As[wr * 64 + mi * 16 + l15][l4 * 8];
    #pragma unroll
    for (int ni = 0; ni < 4; ++ni) bfr[ni] = *(const bf16x8_t*)&Bt[wc * 64 + ni * 16 + l15][l4 * 8];
    #pragma unroll
    for (int mi = 0; mi < 4; ++mi)
      #pragma unroll
      for (int ni = 0; ni < 4; ++ni)
        acc[mi][ni] = __builtin_amdgcn_mfma_f32_16x16x32_bf16(af[mi], bfr[ni], acc[mi][ni], 0, 0, 0);
    __syncthreads();
  }
  // epilogue: +bias, cvt bf16, write panels [b][o>>3][n][o&7]
  bf16* Zb = Zp + (size_t)b * 32 * ((size_t)N_ * 8);
  #pragma unroll
  for (int mi = 0; mi < 4; ++mi) {
    const int obase = m0 + wr * 64 + mi * 16 + l4 * 4;
    const float4 bv = *(const float4*)(bias + obase);
    const size_t gofs = (size_t)(obase >> 3) * ((size_t)N_ * 8) + (obase & 7);
    #pragma unroll
    for (int ni = 0; ni < 4; ++ni) {
      const int nn = n0 + wc * 64 + ni * 16 + l15;
      bf16x4_t o;
      o[0] = (bf16)(acc[mi][ni][0] + bv.x);
      o[1] = (bf16)(acc[mi][ni][1] + bv.y);
      o[2] = (bf16)(acc[mi][ni][2] + bv.z);
      o[3] = (bf16)(acc[mi][ni][3] + bv.w);
      *(bf16x4_t*)(Zb + gofs + (size_t)nn * 8) = o;
    }
  }
}

// ---------------- kernel 5: panel stats -> partials part[sel][c][b] ----------------
__global__ __launch_bounds__(256) void k_stats_p(const bf16* __restrict__ Z, float* __restrict__ part) {
  const int og = blockIdx.x & 31, b = blockIdx.x >> 5;
  const bf16* src = Z + ((size_t)b * 32 + og) * ((size_t)N_ * 8);
  float s[8], q[8];
  #pragma unroll
  for (int j = 0; j < 8; ++j) { s[j] = 0.f; q[j] = 0.f; }
  for (int n = threadIdx.x; n < N_; n += 256) {
    const bf16x8_t v = *(const bf16x8_t*)(src + (size_t)n * 8);
    #pragma unroll
    for (int j = 0; j < 8; ++j) {
      const float f = (float)v[j];
      s[j] += f; q[j] = fmaf(f, f, q[j]);
    }
  }
  #pragma unroll
  for (int off = 1; off < 64; off <<= 1) {
    #pragma unroll
    for (int j = 0; j < 8; ++j) {
      s[j] += __shfl_xor(s[j], off);
      q[j] += __shfl_xor(q[j], off);
    }
  }
  __shared__ float red[4][16];
  const int w = threadIdx.x >> 6;
  if ((threadIdx.x & 63) == 0) {
    #pragma unroll
    for (int j = 0; j < 8; ++j) { red[w][j] = s[j]; red[w][8 + j] = q[j]; }
  }
  __syncthreads();
  if (threadIdx.x < 16) {
    const float t = red[0][threadIdx.x] + red[1][threadIdx.x] + red[2][threadIdx.x] + red[3][threadIdx.x];
    const int sel = threadIdx.x >> 3, j = threadIdx.x & 7;
    part[((size_t)sel * 256 + og * 8 + j) * 8 + b] = t;
  }
}

// ---------------- kernel 6: finalize scale/shift ----------------
__global__ __launch_bounds__(256) void k_ss(const float* __restrict__ part, const float* __restrict__ g,
                                            const float* __restrict__ be, float* __restrict__ ss) {
  const int c = threadIdx.x;
  float s = 0.f, q = 0.f;
  #pragma unroll
  for (int b = 0; b < 8; ++b) { s += part[(size_t)c * 8 + b]; q += part[(256 + (size_t)c) * 8 + b]; }
  const float mean = s * (1.f / 65536.f);
  const float var  = q * (1.f / 65536.f) - mean * mean;
  const float rstd = rsqrtf(var + 1e-5f);
  const float sc = g[c] * rstd;
  ss[c] = sc; ss[O_ + c] = be[c] - mean * sc;
}

// ---------------- kernel 7: in-place BN+ReLU on panels ----------------
__global__ __launch_bounds__(256) void k_apply_p(bf16* __restrict__ Z, const float* __restrict__ ss) {
  const int nc = blockIdx.x & 31, og = (blockIdx.x >> 5) & 31, b = blockIdx.x >> 10;
  const int n = nc * 256 + threadIdx.x;
  bf16* p = Z + (((size_t)b * 32 + og) * N_ + n) * 8;
  bf16x8_t v = *(bf16x8_t*)p;
  #pragma unroll
  for (int j = 0; j < 8; ++j) {
    const int c = og * 8 + j;
    v[j] = (bf16)fmaxf(fmaf((float)v[j], ss[c], ss[O_ + c]), 0.f);
  }
  *(bf16x8_t*)p = v;
}

// ---------------- kernel 8: final BN+ReLU, panels -> Y fp32 [B][256][N] ----------------
__global__ __launch_bounds__(256) void k_final_p(const bf16* __restrict__ Z, const float* __restrict__ ss,
                                                 float* __restrict__ Y) {
  const int b  = blockIdx.x >> 7;
  const int n0 = (blockIdx.x & 127) * 64;
  const int og = threadIdx.x >> 3, ns = threadIdx.x & 7;
  const bf16* src = Z + (((size_t)b * 32 + og) * N_ + n0 + ns * 8) * 8;
  bf16x8_t v[8];
  #pragma unroll
  for (int i = 0; i < 8; ++i) v[i] = *(const bf16x8_t*)(src + i * 8);
  float sc[8], sh[8];
  #pragma unroll
  for (int j = 0; j < 8; ++j) { sc[j] = ss[og * 8 + j]; sh[j] = ss[O_ + og * 8 + j]; }
  float* dst = Y + ((size_t)b * O_ + og * 8) * N_ + n0 + ns * 8;
  #pragma unroll
  for (int j = 0; j < 8; ++j) {
    float4 a0, a1;
    a0.x = fmaxf(fmaf((float)v[0][j], sc[j], sh[j]), 0.f);
    a0.y = fmaxf(fmaf((float)v[1][j], sc[j], sh[j]), 0.f);
    a0.z = fmaxf(fmaf((float)v[2][j], sc[j], sh[j]), 0.f);
    a0.w = fmaxf(fmaf((float)v[3][j], sc[j], sh[j]), 0.f);
    a1.x = fmaxf(fmaf((float)v[4][j], sc[j], sh[j]), 0.f);
    a1.y = fmaxf(fmaf((float)v[5][j], sc[j], sh[j]), 0.f);
    a1.z = fmaxf(fmaf((float)v[6][j], sc[j], sh[j]), 0.f);
    a1.w = fmaxf(fmaf((float)v[7][j], sc[j], sh[j]), 0.f);
    *(float4*)(dst + (size_t)j * N_)     = a0;
    *(float4*)(dst + (size_t)j * N_ + 4) = a1;
  }
}

extern "C" void kernel_launch(void* const* d_in, const int* in_sizes, int n_in,
                              void* d_out, int out_size, void* d_ws, size_t ws_size,
                              hipStream_t stream) {
  const float* xyz1    = (const float*)d_in[0];
  const float* xyz2    = (const float*)d_in[1];
  const float* points1 = (const float*)d_in[2];
  const float* points2 = (const float*)d_in[3];
  const float* W1  = (const float*)d_in[4];
  const float* b1  = (const float*)d_in[5];
  const float* g1  = (const float*)d_in[6];
  const float* be1 = (const float*)d_in[7];
  const float* W2  = (const float*)d_in[8];
  const float* b2  = (const float*)d_in[9];
  const float* g2  = (const float*)d_in[10];
  const float* be2 = (const float*)d_in[11];
  float* Y = (float*)d_out;
  char*  ws = (char*)d_ws;
  int*   idxw = (int*)(ws + OFF_IDX);
  float* www  = (float*)(ws + OFF_W);
  bf16*  xp   = (bf16*)(ws + OFF_XP);
  bf16*  z1   = (bf16*)(ws + OFF_Z);    // also f2t (disjoint lifetime)
  bf16*  f2t  = (bf16*)(ws + OFF_Z);
  bf16*  z2   = (bf16*)(ws + OFF_XP);   // aliases xp (dead after gemm1)
  float* ss1  = (float*)(ws + OFF_SS1);
  float* ss2  = (float*)(ws + OFF_SS2);
  float* part = (float*)(ws + OFF_PART);

  hipLaunchKernelGGL(k_conv_p1, dim3(1024), dim3(256), 0, stream, points1, xp);
  hipLaunchKernelGGL(k_nn3, dim3(128, 8), dim3(256), 0, stream, xyz1, xyz2, idxw, www);
  hipLaunchKernelGGL(k_t2, dim3(1024), dim3(256), 0, stream, points2, f2t);
  hipLaunchKernelGGL(k_interp, dim3(8192), dim3(256), 0, stream, f2t, idxw, www, xp);
  hipLaunchKernelGGL((k_gemm<384>), dim3(64, 2, 8), dim3(256), 0, stream, W1, b1, xp, z1);
  hipLaunchKernelGGL(k_stats_p, dim3(256), dim3(256), 0, stream, z1, part);
  hipLaunchKernelGGL(k_ss, dim3(1), dim3(256), 0, stream, part, g1, be1, ss1);
  hipLaunchKernelGGL(k_apply_p, dim3(8192), dim3(256), 0, stream, z1, ss1);
  hipLaunchKernelGGL((k_gemm<256>), dim3(64, 2, 8), dim3(256), 0, stream, W2, b2, z1, z2);
  hipLaunchKernelGGL(k_stats_p, dim3(256), dim3(256), 0, stream, z2, part);
  hipLaunchKernelGGL(k_ss, dim3(1), dim3(256), 0, stream, part, g2, be2, ss2);
  hipLaunchKernelGGL(k_final_p, dim3(1024), dim3(256), 0, stream, z2, ss2, Y);
}

// Round 6
// 190.814 us; speedup vs baseline: 1.6039x; 1.0292x over previous
//
#include <hip/hip_runtime.h>

#define B_   8
#define N_   8192
#define S_   2048
#define D1_  128
#define D2_  256
#define O_   256
#define BN_  (B_*N_)   // 65536

typedef __bf16 bf16;
typedef __bf16 bf16x8_t __attribute__((ext_vector_type(8)));
typedef __bf16 bf16x4_t __attribute__((ext_vector_type(4)));
typedef float  f32x4_t  __attribute__((ext_vector_type(4)));

// ---------------- workspace layout ----------------
// OFF_IDX region (768KB): idx planes until k_interp; then reused for W bf16 images (k_wprep)
static const size_t OFF_IDX  = 0;
static const size_t OFF_W    = 786432;
static const size_t OFF_XP   = 1572864;   // x panels [B][48][N][8] bf16 (z2 aliases)
static const size_t OFF_Z    = 51904512;  // f2t (t2->interp), then z1 panels [B][32][N][8]
static const size_t OFF_SS1  = 85458944;
static const size_t OFF_SS2  = 85460992;
static const size_t OFF_PART = 85463040;

#define GL16(gsrc, ldst) \
  __builtin_amdgcn_global_load_lds((const __attribute__((address_space(1))) void*)(gsrc), \
                                   (__attribute__((address_space(3))) void*)(ldst), 16, 0, 0)

// ---------------- kernel 1: points1 -> x panels 0..15 (bf16, [B][48][N][8]) ----------------
__global__ __launch_bounds__(256) void k_conv_p1(const float* __restrict__ p1, bf16* __restrict__ xp) {
  const int g  = blockIdx.x * 256 + threadIdx.x;
  const int n4 = g & 2047;
  const int c8 = (g >> 11) & 15;
  const int b  = g >> 15;
  const int n  = n4 * 4;
  const float* src = p1 + ((size_t)b * D1_ + c8 * 8) * N_ + n;
  bf16x8_t o0, o1, o2, o3;
  #pragma unroll
  for (int j = 0; j < 8; ++j) {
    float4 v = *(const float4*)(src + (size_t)j * N_);
    o0[j] = (bf16)v.x; o1[j] = (bf16)v.y; o2[j] = (bf16)v.z; o3[j] = (bf16)v.w;
  }
  bf16* dst = xp + (((size_t)b * 48 + c8) * N_ + n) * 8;
  *(bf16x8_t*)(dst)      = o0;
  *(bf16x8_t*)(dst + 8)  = o1;
  *(bf16x8_t*)(dst + 16) = o2;
  *(bf16x8_t*)(dst + 24) = o3;
}

// ---------------- kernel 2: 3-NN search (EXACT fp32 compare — round-4 known-good) ----------
// NOTE: comparison key precision is a correctness contract. Truncated-mantissa packing
// (round 5) selects wrong neighbors on near-ties -> O(1) feature errors. Keep exact fp32
// strict-< with earlier-index-wins tie semantics (matches reference top_k).
__device__ __forceinline__ void ins3(float d, int i,
                                     float& d0, float& d1, float& d2,
                                     int& i0, int& i1, int& i2) {
  const bool c2 = d < d2, c1 = d < d1, c0 = d < d0;
  const float nd2 = c1 ? d1 : (c2 ? d : d2); const int ni2 = c1 ? i1 : (c2 ? i : i2);
  const float nd1 = c0 ? d0 : (c1 ? d : d1); const int ni1 = c0 ? i0 : (c1 ? i : i1);
  d0 = c0 ? d : d0; i0 = c0 ? i : i0;
  d1 = nd1; i1 = ni1; d2 = nd2; i2 = ni2;
}

__global__ __launch_bounds__(256) void k_nn3(const float* __restrict__ xyz1, const float* __restrict__ xyz2,
                                             int* __restrict__ idxw, float* __restrict__ www) {
  __shared__ float4 sq[4][S_ / 4];   // x,y,z,|q|^2 planes (32 KB)
  __shared__ float  pd[4][64][3];
  __shared__ int    pi[4][64][3];
  const int tid  = threadIdx.x;
  const int lane = tid & 63, w = tid >> 6;     // w = S-chunk 0..3
  const int b     = blockIdx.y;
  const int nbase = blockIdx.x * 64;

  const float* x2 = xyz2 + (size_t)b * 3 * S_;
  for (int j = tid; j < S_ / 4; j += 256) {
    const float4 x = *(const float4*)(x2 + 4 * j);
    const float4 y = *(const float4*)(x2 + S_ + 4 * j);
    const float4 z = *(const float4*)(x2 + 2 * S_ + 4 * j);
    float4 qq;
    qq.x = fmaf(x.x, x.x, fmaf(y.x, y.x, z.x * z.x));
    qq.y = fmaf(x.y, x.y, fmaf(y.y, y.y, z.y * z.y));
    qq.z = fmaf(x.z, x.z, fmaf(y.z, y.z, z.z * z.z));
    qq.w = fmaf(x.w, x.w, fmaf(y.w, y.w, z.w * z.w));
    sq[0][j] = x; sq[1][j] = y; sq[2][j] = z; sq[3][j] = qq;
  }

  const int n = nbase + lane;
  const float* x1 = xyz1 + (size_t)b * 3 * N_;
  const float px = x1[n], py = x1[N_ + n], pz = x1[2 * N_ + n];
  const float ax = -2.f * px, ay = -2.f * py, az = -2.f * pz;
  __syncthreads();

  float e0 = 3.4e38f, e1 = 3.4e38f, e2 = 3.4e38f;
  int   i0 = 0, i1 = 0, i2 = 0;

  const int jb = w * (S_ / 16);    // 128 float4 groups per chunk
  #pragma unroll 4
  for (int j = jb; j < jb + S_ / 16; ++j) {
    const float4 qx = sq[0][j], qy = sq[1][j], qz = sq[2][j], qq = sq[3][j];
    #define CAND(C, SI)                                                        \
      {                                                                        \
        const float E = fmaf(ax, qx.C, fmaf(ay, qy.C, fmaf(az, qz.C, qq.C))); \
        const bool l0 = E < e0, l1 = E < e1, l2 = E < e2;                      \
        const int ni1 = l0 ? i0 : (l1 ? (SI) : i1);                            \
        const int ni2 = l1 ? i1 : (l2 ? (SI) : i2);                            \
        i0 = l0 ? (SI) : i0; i1 = ni1; i2 = ni2;                               \
        const float ne1 = __builtin_amdgcn_fmed3f(E, e0, e1);                  \
        const float ne2 = __builtin_amdgcn_fmed3f(E, e1, e2);                  \
        e0 = fminf(E, e0); e1 = ne1; e2 = ne2;                                 \
      }
    CAND(x, 4 * j + 0)
    CAND(y, 4 * j + 1)
    CAND(z, 4 * j + 2)
    CAND(w, 4 * j + 3)
    #undef CAND
  }

  const float pp = fmaf(px, px, fmaf(py, py, pz * pz));
  pd[w][lane][0] = e0 + pp; pd[w][lane][1] = e1 + pp; pd[w][lane][2] = e2 + pp;
  pi[w][lane][0] = i0; pi[w][lane][1] = i1; pi[w][lane][2] = i2;
  __syncthreads();

  if (tid < 64) {
    float d0 = pd[0][tid][0], d1 = pd[0][tid][1], d2 = pd[0][tid][2];
    int   j0 = pi[0][tid][0], j1 = pi[0][tid][1], j2 = pi[0][tid][2];
    #pragma unroll
    for (int ck = 1; ck < 4; ++ck)
      #pragma unroll
      for (int k = 0; k < 3; ++k)
        ins3(pd[ck][tid][k], pi[ck][tid][k], d0, d1, d2, j0, j1, j2);
    const float r0 = 1.f / (d0 + 1e-8f), r1 = 1.f / (d1 + 1e-8f), r2 = 1.f / (d2 + 1e-8f);
    const float inv = 1.f / (r0 + r1 + r2);
    const int bn = b * N_ + nbase + tid;
    idxw[bn] = j0; idxw[BN_ + bn] = j1; idxw[2 * BN_ + bn] = j2;
    www[bn] = r0 * inv; www[BN_ + bn] = r1 * inv; www[2 * BN_ + bn] = r2 * inv;
  }
}

// ---------------- kernel 3a: transpose points2 (B,256,2048) f32 -> f2t (B,2048,256) bf16 ------
__global__ __launch_bounds__(256) void k_t2(const float* __restrict__ p2, bf16* __restrict__ f2t) {
  __shared__ float lds[64][65];
  const int bid = blockIdx.x;
  const int b = bid & 7;
  const int inner = bid >> 3;
  const int s0 = (inner & 31) * 64;
  const int c0 = (inner >> 5) * 64;
  const int t = threadIdx.x;
  {
    const int cr = t >> 2, scb = (t & 3) * 16;
    const float* src = p2 + ((size_t)b * D2_ + c0 + cr) * S_ + s0 + scb;
    #pragma unroll
    for (int i = 0; i < 4; ++i) {
      const float4 v = *(const float4*)(src + 4 * i);
      lds[cr][scb + 4 * i + 0] = v.x; lds[cr][scb + 4 * i + 1] = v.y;
      lds[cr][scb + 4 * i + 2] = v.z; lds[cr][scb + 4 * i + 3] = v.w;
    }
  }
  __syncthreads();
  const int co = (t & 7) * 8;
  #pragma unroll
  for (int pass = 0; pass < 2; ++pass) {
    const int s = pass * 32 + (t >> 3);
    bf16x8_t o;
    #pragma unroll
    for (int j = 0; j < 8; ++j) o[j] = (bf16)lds[co + j][s];
    *(bf16x8_t*)(f2t + ((size_t)b * S_ + s0 + s) * D2_ + c0 + co) = o;
  }
}

// ---------------- kernel 3b: gather-interp -> x panels 16..47 ----------------
__global__ __launch_bounds__(256) void k_interp(const bf16* __restrict__ f2t, const int* __restrict__ idxw,
                                                const float* __restrict__ www, bf16* __restrict__ xp) {
  const int bid = blockIdx.x;
  const int b = bid & 7;
  const int n = (bid >> 3) * 8 + (threadIdx.x & 7);
  const int c8 = threadIdx.x >> 3;
  const int bn = b * N_ + n;
  const int j0 = idxw[bn], j1 = idxw[BN_ + bn], j2 = idxw[2 * BN_ + bn];
  const float w0 = www[bn], w1 = www[BN_ + bn], w2 = www[2 * BN_ + bn];
  const bf16* base = f2t + (size_t)b * S_ * D2_ + c8 * 8;
  const bf16x8_t v0 = *(const bf16x8_t*)(base + (size_t)j0 * D2_);
  const bf16x8_t v1 = *(const bf16x8_t*)(base + (size_t)j1 * D2_);
  const bf16x8_t v2 = *(const bf16x8_t*)(base + (size_t)j2 * D2_);
  bf16x8_t out;
  #pragma unroll
  for (int j = 0; j < 8; ++j)
    out[j] = (bf16)(w0 * (float)v0[j] + w1 * (float)v1[j] + w2 * (float)v2[j]);
  *(bf16x8_t*)(xp + (((size_t)b * 48 + 16 + c8) * N_ + (size_t)n) * 8) = out;
}

// ---------------- kernel 3c: W fp32 -> bf16 LDS-image panels ----------------
// image layout per (mblk,kt32): [kc(4)][row(128)][kk(8)] bf16, 4096 elems
__global__ __launch_bounds__(256) void k_wprep(const float* __restrict__ W1, const float* __restrict__ W2,
                                               bf16* __restrict__ img) {
  const int g = blockIdx.x * 256 + threadIdx.x;   // 80 blocks
  if (g < 12288) {
    const int e = g * 8;
    const int imgblk = e >> 12, r = e & 4095;
    const int kc = r >> 10, row = (r & 1023) >> 3;
    const int mblk = imgblk / 12, kt32 = imgblk % 12;
    const float* s = W1 + (size_t)(mblk * 128 + row) * 384 + kt32 * 32 + kc * 8;
    const float4 f0 = *(const float4*)(s), f1 = *(const float4*)(s + 4);
    bf16x8_t h;
    h[0] = (bf16)f0.x; h[1] = (bf16)f0.y; h[2] = (bf16)f0.z; h[3] = (bf16)f0.w;
    h[4] = (bf16)f1.x; h[5] = (bf16)f1.y; h[6] = (bf16)f1.z; h[7] = (bf16)f1.w;
    *(bf16x8_t*)(img + e) = h;
  } else if (g < 20480) {
    const int e = (g - 12288) * 8;
    const int imgblk = e >> 12, r = e & 4095;
    const int kc = r >> 10, row = (r & 1023) >> 3;
    const int mblk = imgblk >> 3, kt32 = imgblk & 7;
    const float* s = W2 + (size_t)(mblk * 128 + row) * 256 + kt32 * 32 + kc * 8;
    const float4 f0 = *(const float4*)(s), f1 = *(const float4*)(s + 4);
    bf16x8_t h;
    h[0] = (bf16)f0.x; h[1] = (bf16)f0.y; h[2] = (bf16)f0.z; h[3] = (bf16)f0.w;
    h[4] = (bf16)f1.x; h[5] = (bf16)f1.y; h[6] = (bf16)f1.z; h[7] = (bf16)f1.w;
    *(bf16x8_t*)(img + 98304 + e) = h;
  }
}

// ---------------- kernel 4: GEMM via global_load_lds, XCD-swizzled ----------------
template<int K>
__global__ __launch_bounds__(256) void k_gemm(const bf16* __restrict__ Wimg, const float* __restrict__ bias,
                                              const bf16* __restrict__ X, bf16* __restrict__ Zp) {
  __shared__ bf16 As[4096];   // [kc(4)][row m(128)][kk(8)]
  __shared__ bf16 Bt[4096];   // [kc(4)][row n(128)][kk(8)]
  const int tid = threadIdx.x;
  const int lane = tid & 63, wid = tid >> 6;
  const int wr = wid >> 1, wc = wid & 1;
  const int dd = blockIdx.x;
  const int xcd = dd & 7, pos = dd >> 3;
  const int b = pos >> 4, q = pos & 15;
  const int m0 = (q & 1) * 128;
  const int n0 = (xcd * 8 + (q >> 1)) * 128;
  const int mblk = m0 >> 7;
  const int l15 = lane & 15, l4 = lane >> 4;

  f32x4_t acc[4][4];
  #pragma unroll
  for (int i = 0; i < 4; ++i)
    #pragma unroll
    for (int j = 0; j < 4; ++j) { f32x4_t z = {0.f, 0.f, 0.f, 0.f}; acc[i][j] = z; }

  const bf16* Xb = X + (size_t)b * (K / 8) * ((size_t)N_ * 8);

  for (int kt = 0; kt < K; kt += 32) {
    const bf16* asrc = Wimg + (size_t)(mblk * (K / 32) + (kt >> 5)) * 4096 + wid * 1024 + lane * 8;
    GL16(asrc,       &As[wid * 1024]);
    GL16(asrc + 512, &As[wid * 1024 + 512]);
    const bf16* bsrc = Xb + ((size_t)(kt >> 3) + wid) * ((size_t)N_ * 8) + ((size_t)n0 + lane) * 8;
    GL16(bsrc,       &Bt[wid * 1024]);
    GL16(bsrc + 512, &Bt[wid * 1024 + 512]);
    __syncthreads();
    bf16x8_t af[4], bfr[4];
    #pragma unroll
    for (int mi = 0; mi < 4; ++mi) af[mi]  = *(const bf16x8_t*)&As[l4 * 1024 + (wr * 64 + mi * 16 + l15) * 8];
    #pragma unroll
    for (int ni = 0; ni < 4; ++ni) bfr[ni] = *(const bf16x8_t*)&Bt[l4 * 1024 + (wc * 64 + ni * 16 + l15) * 8];
    #pragma unroll
    for (int mi = 0; mi < 4; ++mi)
      #pragma unroll
      for (int ni = 0; ni < 4; ++ni)
        acc[mi][ni] = __builtin_amdgcn_mfma_f32_16x16x32_bf16(af[mi], bfr[ni], acc[mi][ni], 0, 0, 0);
    __syncthreads();
  }
  bf16* Zb = Zp + (size_t)b * 32 * ((size_t)N_ * 8);
  #pragma unroll
  for (int mi = 0; mi < 4; ++mi) {
    const int obase = m0 + wr * 64 + mi * 16 + l4 * 4;
    const float4 bv = *(const float4*)(bias + obase);
    const size_t gofs = (size_t)(obase >> 3) * ((size_t)N_ * 8) + (obase & 7);
    #pragma unroll
    for (int ni = 0; ni < 4; ++ni) {
      const int nn = n0 + wc * 64 + ni * 16 + l15;
      bf16x4_t o;
      o[0] = (bf16)(acc[mi][ni][0] + bv.x);
      o[1] = (bf16)(acc[mi][ni][1] + bv.y);
      o[2] = (bf16)(acc[mi][ni][2] + bv.z);
      o[3] = (bf16)(acc[mi][ni][3] + bv.w);
      *(bf16x4_t*)(Zb + gofs + (size_t)nn * 8) = o;
    }
  }
}

// ---------------- kernel 5: panel stats -> partials ----------------
__global__ __launch_bounds__(256) void k_stats_p(const bf16* __restrict__ Z, float* __restrict__ part) {
  const int og = blockIdx.x & 31, b = blockIdx.x >> 5;
  const bf16* src = Z + ((size_t)b * 32 + og) * ((size_t)N_ * 8);
  float s[8], q[8];
  #pragma unroll
  for (int j = 0; j < 8; ++j) { s[j] = 0.f; q[j] = 0.f; }
  for (int n = threadIdx.x; n < N_; n += 256) {
    const bf16x8_t v = *(const bf16x8_t*)(src + (size_t)n * 8);
    #pragma unroll
    for (int j = 0; j < 8; ++j) {
      const float f = (float)v[j];
      s[j] += f; q[j] = fmaf(f, f, q[j]);
    }
  }
  #pragma unroll
  for (int off = 1; off < 64; off <<= 1) {
    #pragma unroll
    for (int j = 0; j < 8; ++j) {
      s[j] += __shfl_xor(s[j], off);
      q[j] += __shfl_xor(q[j], off);
    }
  }
  __shared__ float red[4][16];
  const int w = threadIdx.x >> 6;
  if ((threadIdx.x & 63) == 0) {
    #pragma unroll
    for (int j = 0; j < 8; ++j) { red[w][j] = s[j]; red[w][8 + j] = q[j]; }
  }
  __syncthreads();
  if (threadIdx.x < 16) {
    const float t = red[0][threadIdx.x] + red[1][threadIdx.x] + red[2][threadIdx.x] + red[3][threadIdx.x];
    const int sel = threadIdx.x >> 3, j = threadIdx.x & 7;
    part[((size_t)sel * 256 + og * 8 + j) * 8 + b] = t;
  }
}

// ---------------- kernel 6: finalize scale/shift ----------------
__global__ __launch_bounds__(256) void k_ss(const float* __restrict__ part, const float* __restrict__ g,
                                            const float* __restrict__ be, float* __restrict__ ss) {
  const int c = threadIdx.x;
  float s = 0.f, q = 0.f;
  #pragma unroll
  for (int b = 0; b < 8; ++b) { s += part[(size_t)c * 8 + b]; q += part[(256 + (size_t)c) * 8 + b]; }
  const float mean = s * (1.f / 65536.f);
  const float var  = q * (1.f / 65536.f) - mean * mean;
  const float rstd = rsqrtf(var + 1e-5f);
  const float sc = g[c] * rstd;
  ss[c] = sc; ss[O_ + c] = be[c] - mean * sc;
}

// ---------------- kernel 7: in-place BN+ReLU on panels ----------------
__global__ __launch_bounds__(256) void k_apply_p(bf16* __restrict__ Z, const float* __restrict__ ss) {
  const int nc = blockIdx.x & 31, og = (blockIdx.x >> 5) & 31, b = blockIdx.x >> 10;
  const int n = nc * 256 + threadIdx.x;
  bf16* p = Z + (((size_t)b * 32 + og) * N_ + n) * 8;
  bf16x8_t v = *(bf16x8_t*)p;
  #pragma unroll
  for (int j = 0; j < 8; ++j) {
    const int c = og * 8 + j;
    v[j] = (bf16)fmaxf(fmaf((float)v[j], ss[c], ss[O_ + c]), 0.f);
  }
  *(bf16x8_t*)p = v;
}

// ---------------- kernel 8: final BN+ReLU, panels -> Y fp32 [B][256][N] ----------------
__global__ __launch_bounds__(256) void k_final_p(const bf16* __restrict__ Z, const float* __restrict__ ss,
                                                 float* __restrict__ Y) {
  const int b  = blockIdx.x >> 7;
  const int n0 = (blockIdx.x & 127) * 64;
  const int og = threadIdx.x >> 3, ns = threadIdx.x & 7;
  const bf16* src = Z + (((size_t)b * 32 + og) * N_ + n0 + ns * 8) * 8;
  bf16x8_t v[8];
  #pragma unroll
  for (int i = 0; i < 8; ++i) v[i] = *(const bf16x8_t*)(src + i * 8);
  float sc[8], sh[8];
  #pragma unroll
  for (int j = 0; j < 8; ++j) { sc[j] = ss[og * 8 + j]; sh[j] = ss[O_ + og * 8 + j]; }
  float* dst = Y + ((size_t)b * O_ + og * 8) * N_ + n0 + ns * 8;
  #pragma unroll
  for (int j = 0; j < 8; ++j) {
    float4 a0, a1;
    a0.x = fmaxf(fmaf((float)v[0][j], sc[j], sh[j]), 0.f);
    a0.y = fmaxf(fmaf((float)v[1][j], sc[j], sh[j]), 0.f);
    a0.z = fmaxf(fmaf((float)v[2][j], sc[j], sh[j]), 0.f);
    a0.w = fmaxf(fmaf((float)v[3][j], sc[j], sh[j]), 0.f);
    a1.x = fmaxf(fmaf((float)v[4][j], sc[j], sh[j]), 0.f);
    a1.y = fmaxf(fmaf((float)v[5][j], sc[j], sh[j]), 0.f);
    a1.z = fmaxf(fmaf((float)v[6][j], sc[j], sh[j]), 0.f);
    a1.w = fmaxf(fmaf((float)v[7][j], sc[j], sh[j]), 0.f);
    *(float4*)(dst + (size_t)j * N_)     = a0;
    *(float4*)(dst + (size_t)j * N_ + 4) = a1;
  }
}

extern "C" void kernel_launch(void* const* d_in, const int* in_sizes, int n_in,
                              void* d_out, int out_size, void* d_ws, size_t ws_size,
                              hipStream_t stream) {
  const float* xyz1    = (const float*)d_in[0];
  const float* xyz2    = (const float*)d_in[1];
  const float* points1 = (const float*)d_in[2];
  const float* points2 = (const float*)d_in[3];
  const float* W1  = (const float*)d_in[4];
  const float* b1  = (const float*)d_in[5];
  const float* g1  = (const float*)d_in[6];
  const float* be1 = (const float*)d_in[7];
  const float* W2  = (const float*)d_in[8];
  const float* b2  = (const float*)d_in[9];
  const float* g2  = (const float*)d_in[10];
  const float* be2 = (const float*)d_in[11];
  float* Y = (float*)d_out;
  char*  ws = (char*)d_ws;
  int*   idxw  = (int*)(ws + OFF_IDX);
  float* www   = (float*)(ws + OFF_W);
  bf16*  wimg1 = (bf16*)(ws + OFF_IDX);   // reuses idx region AFTER k_interp
  bf16*  wimg2 = wimg1 + 98304;
  bf16*  xp    = (bf16*)(ws + OFF_XP);
  bf16*  z1    = (bf16*)(ws + OFF_Z);     // also f2t (disjoint lifetime)
  bf16*  f2t   = (bf16*)(ws + OFF_Z);
  bf16*  z2    = (bf16*)(ws + OFF_XP);    // aliases xp (dead after gemm1)
  float* ss1   = (float*)(ws + OFF_SS1);
  float* ss2   = (float*)(ws + OFF_SS2);
  float* part  = (float*)(ws + OFF_PART);

  hipLaunchKernelGGL(k_conv_p1, dim3(1024), dim3(256), 0, stream, points1, xp);
  hipLaunchKernelGGL(k_nn3, dim3(128, 8), dim3(256), 0, stream, xyz1, xyz2, idxw, www);
  hipLaunchKernelGGL(k_t2, dim3(1024), dim3(256), 0, stream, points2, f2t);
  hipLaunchKernelGGL(k_interp, dim3(8192), dim3(256), 0, stream, f2t, idxw, www, xp);
  hipLaunchKernelGGL(k_wprep, dim3(80), dim3(256), 0, stream, W1, W2, wimg1);
  hipLaunchKernelGGL((k_gemm<384>), dim3(1024), dim3(256), 0, stream, wimg1, b1, xp, z1);
  hipLaunchKernelGGL(k_stats_p, dim3(256), dim3(256), 0, stream, z1, part);
  hipLaunchKernelGGL(k_ss, dim3(1), dim3(256), 0, stream, part, g1, be1, ss1);
  hipLaunchKernelGGL(k_apply_p, dim3(8192), dim3(256), 0, stream, z1, ss1);
  hipLaunchKernelGGL((k_gemm<256>), dim3(1024), dim3(256), 0, stream, wimg2, b2, z1, z2);
  hipLaunchKernelGGL(k_stats_p, dim3(256), dim3(256), 0, stream, z2, part);
  hipLaunchKernelGGL(k_ss, dim3(1), dim3(256), 0, stream, part, g2, be2, ss2);
  hipLaunchKernelGGL(k_final_p, dim3(1024), dim3(256), 0, stream, z2, ss2, Y);
}